// Round 9
// baseline (24417.706 us; speedup 1.0000x reference)
//
#include <hip/hip_runtime.h>
#include <cstdint>
#include <cstddef>

// SQACILSTM round 13: resubmit of round 12 (container failed twice = infra
// flake; kernel re-audited: block-uniform barriers, matched red[] producer/
// consumer pairs, full coverage, aligned f4 staging - no defect found).
// r11 base (17.1ms, FETCH 1.25e6 KB, weights L2-resident via XCD pairing)
// + wave-level TLP without touching the block<->slice map: SAME 72 blocks,
// SAME slice assignments, 512 threads (8 waves = 2/SIMD). PA/gates split M
// across wave-halves (no reduction); PB-cell/PB-fuse split K with 16KB LDS
// partial reduce. B-loads duplicate (L2 hits -> FETCH should stay ~1.25e6,
// falsifiable). Staging chains shorten (2x threads/row). LDS 136KB <= 160.

#define T_   256
#define B_   64
#define NBLK 72
#define NTHR 512
#define GRIDTH (NBLK*NTHR)
#define HALL 12582912   // 256*64*768

typedef __attribute__((ext_vector_type(8))) short short8;
typedef __attribute__((ext_vector_type(4))) float f4;
typedef unsigned long long u64t;
typedef unsigned short u16t;
typedef unsigned int u32t;

struct Params {
  const float* question; const float* answer; const float* x; const int* ping;
  const float* h0; const float* c0;
  const float* Wqh; const float* bqh; const float* Wah; const float* bah;
  const float* Wih; const float* bih; const float* Whh; const float* bhh;
  const float* Wq;  const float* bq;  const float* Wk;  const float* bk;
  const float* Wv;  const float* bv;  const float* Wfuse; const float* bfuse;
  float* out;
  u32t* flags; u32t* gen;
  u16t* Wqkv_s; u16t* Whhih_s; u16t* Wfuse_s; u16t* Wcomb_s; u16t* Wfuse_bf;
  float* base; float* gatesHX; u16t* ctxb; u16t* hB; float* cbuf; float* bfW;
  u16t* xB;
};

__device__ __forceinline__ u16t f2b(float f){
  union { float f; u32t u; } a; a.f = f;
  u32t u = a.u;
  u32t r = u + 0x7FFFu + ((u >> 16) & 1u);
  return (u16t)(r >> 16);
}
__device__ __forceinline__ float b2f(u16t u){
  union { u32t u; float f; } a; a.u = ((u32t)u) << 16; return a.f;
}
__device__ __forceinline__ u64t pack4f(float a, float b, float c, float d){
  return (u64t)f2b(a) | ((u64t)f2b(b)<<16) | ((u64t)f2b(c)<<32) | ((u64t)f2b(d)<<48);
}
__device__ __forceinline__ float sigm(float x){ return 1.0f/(1.0f+__expf(-x)); }
__device__ __forceinline__ float tanh_(float x){ return 2.0f/(1.0f+__expf(-2.0f*x)) - 1.0f; }
__device__ __forceinline__ f4 mfma16(short8 a, short8 b, f4 c){
  return __builtin_amdgcn_mfma_f32_16x16x32_bf16(a, b, c, 0, 0, 0);
}
__device__ __forceinline__ float wsum(float x){
  #pragma unroll
  for (int off = 32; off > 0; off >>= 1) x += __shfl_xor(x, off, 64);
  return x;
}

// ---- batched coherent loads (LLC / sc0 sc1), one waitcnt per batch ----
__device__ __forceinline__ void cldx4_8(f4&d0,f4&d1,f4&d2,f4&d3,f4&d4,f4&d5,f4&d6,f4&d7,
  const void*a0,const void*a1,const void*a2,const void*a3,
  const void*a4,const void*a5,const void*a6,const void*a7){
  asm volatile(
    "global_load_dwordx4 %0, %8, off sc0 sc1\n\t"
    "global_load_dwordx4 %1, %9, off sc0 sc1\n\t"
    "global_load_dwordx4 %2, %10, off sc0 sc1\n\t"
    "global_load_dwordx4 %3, %11, off sc0 sc1\n\t"
    "global_load_dwordx4 %4, %12, off sc0 sc1\n\t"
    "global_load_dwordx4 %5, %13, off sc0 sc1\n\t"
    "global_load_dwordx4 %6, %14, off sc0 sc1\n\t"
    "global_load_dwordx4 %7, %15, off sc0 sc1\n\t"
    "s_waitcnt vmcnt(0)"
    : "=&v"(d0),"=&v"(d1),"=&v"(d2),"=&v"(d3),"=&v"(d4),"=&v"(d5),"=&v"(d6),"=&v"(d7)
    : "v"(a0),"v"(a1),"v"(a2),"v"(a3),"v"(a4),"v"(a5),"v"(a6),"v"(a7));
}
__device__ __forceinline__ void cldx4_6(f4&d0,f4&d1,f4&d2,f4&d3,f4&d4,f4&d5,
  const void*a0,const void*a1,const void*a2,const void*a3,
  const void*a4,const void*a5){
  asm volatile(
    "global_load_dwordx4 %0, %6, off sc0 sc1\n\t"
    "global_load_dwordx4 %1, %7, off sc0 sc1\n\t"
    "global_load_dwordx4 %2, %8, off sc0 sc1\n\t"
    "global_load_dwordx4 %3, %9, off sc0 sc1\n\t"
    "global_load_dwordx4 %4, %10, off sc0 sc1\n\t"
    "global_load_dwordx4 %5, %11, off sc0 sc1\n\t"
    "s_waitcnt vmcnt(0)"
    : "=&v"(d0),"=&v"(d1),"=&v"(d2),"=&v"(d3),"=&v"(d4),"=&v"(d5)
    : "v"(a0),"v"(a1),"v"(a2),"v"(a3),"v"(a4),"v"(a5));
}
__device__ __forceinline__ void cldx4_4(f4&d0,f4&d1,f4&d2,f4&d3,
  const void*a0,const void*a1,const void*a2,const void*a3){
  asm volatile(
    "global_load_dwordx4 %0, %4, off sc0 sc1\n\t"
    "global_load_dwordx4 %1, %5, off sc0 sc1\n\t"
    "global_load_dwordx4 %2, %6, off sc0 sc1\n\t"
    "global_load_dwordx4 %3, %7, off sc0 sc1\n\t"
    "s_waitcnt vmcnt(0)"
    : "=&v"(d0),"=&v"(d1),"=&v"(d2),"=&v"(d3)
    : "v"(a0),"v"(a1),"v"(a2),"v"(a3));
}
__device__ __forceinline__ void cldd8(float&d0,float&d1,float&d2,float&d3,float&d4,float&d5,float&d6,float&d7,
  const float*a0,const float*a1,const float*a2,const float*a3,
  const float*a4,const float*a5,const float*a6,const float*a7){
  asm volatile(
    "global_load_dword %0, %8, off sc0 sc1\n\t"
    "global_load_dword %1, %9, off sc0 sc1\n\t"
    "global_load_dword %2, %10, off sc0 sc1\n\t"
    "global_load_dword %3, %11, off sc0 sc1\n\t"
    "global_load_dword %4, %12, off sc0 sc1\n\t"
    "global_load_dword %5, %13, off sc0 sc1\n\t"
    "global_load_dword %6, %14, off sc0 sc1\n\t"
    "global_load_dword %7, %15, off sc0 sc1\n\t"
    "s_waitcnt vmcnt(0)"
    : "=&v"(d0),"=&v"(d1),"=&v"(d2),"=&v"(d3),"=&v"(d4),"=&v"(d5),"=&v"(d6),"=&v"(d7)
    : "v"(a0),"v"(a1),"v"(a2),"v"(a3),"v"(a4),"v"(a5),"v"(a6),"v"(a7));
}

// ---- coherent stores (fire-and-forget; drained by barrier's vmcnt wait) ----
__device__ __forceinline__ void cstf(float* p, float v){
  __hip_atomic_store(p, v, __ATOMIC_RELAXED, __HIP_MEMORY_SCOPE_AGENT);
}
__device__ __forceinline__ void cst32(u32t* p, u32t v){
  __hip_atomic_store(p, v, __ATOMIC_RELAXED, __HIP_MEMORY_SCOPE_AGENT);
}

// ---- LDS A-tile, XOR-swizzled 16B chunks ----
__device__ __forceinline__ void aput16(u16t* As, int rowu16, int m, int cc, f4 v){
  int slot = (cc & ~7) | ((cc ^ m) & 7);
  *(f4*)(As + m*rowu16 + slot*8) = v;
}
__device__ __forceinline__ short8 afrag(const u16t* As, int rowu16, int m, int kb, int q4){
  int c = kb*4 + q4;
  int phys = (c & ~7) | ((c ^ m) & 7);
  return *(const short8*)(As + m*rowu16 + phys*8);
}

// ---- grid barrier: relaxed agent atomics only, no cache invalidation ----
__device__ __forceinline__ void gsync(u32t* flags, u32t* gen, u32t e){
  asm volatile("s_waitcnt vmcnt(0) lgkmcnt(0)" ::: "memory");
  __syncthreads();
  if (blockIdx.x == 0){
    if (threadIdx.x > 0 && threadIdx.x < NBLK){
      while (__hip_atomic_load(flags + threadIdx.x*32, __ATOMIC_RELAXED, __HIP_MEMORY_SCOPE_AGENT) < e)
        __builtin_amdgcn_s_sleep(1);
    }
    __syncthreads();
    if (threadIdx.x == 0)
      __hip_atomic_store(gen, e, __ATOMIC_RELAXED, __HIP_MEMORY_SCOPE_AGENT);
  } else {
    if (threadIdx.x == 0){
      __hip_atomic_store(flags + blockIdx.x*32, e, __ATOMIC_RELAXED, __HIP_MEMORY_SCOPE_AGENT);
      while (__hip_atomic_load(gen, __ATOMIC_RELAXED, __HIP_MEMORY_SCOPE_AGENT) < e)
        __builtin_amdgcn_s_sleep(1);
    }
  }
  __builtin_amdgcn_fence(__ATOMIC_ACQUIRE, "workgroup");
  __syncthreads();
}

__launch_bounds__(NTHR, 1)
__global__ void sqac_kernel(Params p){
  extern __shared__ u16t As[];           // 96KB dynamic A-tile
  __shared__ u16t qkvs[64*192];          // 24KB qkv exchange (PA only)
  __shared__ float red[4][64][16];       // 16KB K-split partial reduce (PB only)
  __shared__ int anyX;
  const int tid0 = threadIdx.x;
  const int blk  = blockIdx.x;
  const int tid  = blk*NTHR + tid0;
  const int lane = tid0 & 63;
  const int wv   = tid0 >> 6;            // 0..7
  const int c16  = lane & 15, q4 = lane >> 4;
  u32t e = 0;

  // ================= P0 stage 1: conversions / swizzles / base =================
  {
    for (int idx = tid; idx < 12288; idx += GRIDTH){
      f4 h = *(const f4*)(p.h0 + idx*4);
      *(u64t*)(p.hB + idx*4) = pack4f(h.x, h.y, h.z, h.w);
      *(f4*)(p.cbuf + idx*4) = *(const f4*)(p.c0 + idx*4);
    }
    for (int idx = tid; idx < 3145728; idx += GRIDTH){
      f4 v = *(const f4*)(p.x + (size_t)idx*4);
      *(u64t*)(p.xB + (size_t)idx*4) = pack4f(v.x, v.y, v.z, v.w);
    }
    for (int idx = tid; idx < 221184; idx += GRIDTH){
      int l = idx & 63, g2 = idx >> 6;
      int ntl = g2 % 12, kb = (g2/12) % 24, h = g2/288;
      int k0 = kb*32 + ((l>>4)<<3);
      int nl = ntl*16 + (l&15);
      const float* s; int col;
      if (nl < 64){ s = p.Wq; col = h*64 + nl; }
      else if (nl < 128){ s = p.Wk; col = h*64 + nl - 64; }
      else { s = p.Wv; col = h*64 + nl - 128; }
      union { u16t a[8]; short8 v; } t8;
      #pragma unroll
      for (int j = 0; j < 8; j++) t8.a[j] = f2b(s[(size_t)(k0+j)*768 + col]);
      *(short8*)(p.Wqkv_s + (size_t)idx*8) = t8.v;
    }
    for (int idx = tid; idx < 589824; idx += GRIDTH){
      int l = idx & 63, g2 = idx >> 6;
      int nb = g2 % 192, kb2 = g2 / 192;
      int n  = nb*16 + (l&15);
      int kl = (kb2 % 24)*32 + ((l>>4)<<3);
      const float* s = (kb2 < 24) ? p.Whh : p.Wih;
      union { u16t a[8]; short8 v; } t8;
      #pragma unroll
      for (int j = 0; j < 8; j++) t8.a[j] = f2b(s[(size_t)(kl+j)*3072 + n]);
      *(short8*)(p.Whhih_s + (size_t)idx*8) = t8.v;
    }
    for (int idx = tid; idx < 147456; idx += GRIDTH){
      int l = idx & 63, g2 = idx >> 6;
      int nb = g2 % 48, kb = g2 / 48;
      int n  = nb*16 + (l&15);
      int k0 = kb*32 + ((l>>4)<<3);
      union { u16t a[8]; short8 v; } t8;
      #pragma unroll
      for (int j = 0; j < 8; j++) t8.a[j] = f2b(p.Wfuse[(size_t)(k0+j)*768 + n]);
      *(short8*)(p.Wfuse_s + (size_t)idx*8) = t8.v;
    }
    for (int idx = tid; idx < 294912; idx += GRIDTH){
      f4 v = *(const f4*)(p.Wfuse + idx*4);
      *(u64t*)(p.Wfuse_bf + idx*4) = pack4f(v.x, v.y, v.z, v.w);
    }
    for (int w = tid; w < 24576; w += GRIDTH){
      int bg = w / 3072, n = w - bg*3072;
      float acc[8];
      #pragma unroll
      for (int bi = 0; bi < 8; bi++) acc[bi] = 0.f;
      for (int k = 0; k < 768; k++){
        float wq = p.Wqh[(size_t)k*3072 + n];
        float wa = p.Wah[(size_t)k*3072 + n];
        #pragma unroll
        for (int bi = 0; bi < 8; bi++){
          int b = bg*8 + bi;
          acc[bi] += p.question[b*768 + k]*wq + p.answer[b*768 + k]*wa;
        }
      }
      float bias = p.bqh[n] + p.bah[n] + p.bih[n] + p.bhh[n];
      #pragma unroll
      for (int bi = 0; bi < 8; bi++)
        p.base[(size_t)(bg*8+bi)*3072 + n] = acc[bi] + bias;
    }
    for (int n = tid; n < 3072; n += GRIDTH){
      float a = 0.f;
      for (int k = 0; k < 768; k++) a += p.bfuse[k]*p.Wih[(size_t)k*3072 + n];
      p.bfW[n] = a;
    }
  }
  __threadfence();
  e++; gsync(p.flags, p.gen, e);

  // ================= P0 stage 2: Wcomb = Wfuse @ Wih (MFMA) =================
  {
    int w = tid >> 6;                    // 0..575
    int mt = w % 96, ntg = w / 96;       // ntg 0..5, 32 nt each
    for (int nt = ntg*32; nt < ntg*32 + 32; nt++){
      f4 acc = {0.f,0.f,0.f,0.f};
      for (int kb = 0; kb < 24; kb++){
        short8 af = *(const short8*)(p.Wfuse_bf + (size_t)(mt*16 + c16)*768 + kb*32 + q4*8);
        short8 bf = *(const short8*)(p.Whhih_s + ((size_t)((24+kb)*192 + nt))*512 + lane*8);
        acc = mfma16(af, bf, acc);
      }
      #pragma unroll
      for (int r = 0; r < 4; r++){
        int k1 = mt*16 + q4*4 + r;
        p.Wcomb_s[((size_t)((k1>>5)*192 + nt))*512 + (size_t)((((k1>>3)&3)*16 + c16)*8 + (k1&7))] = f2b(acc[r]);
      }
    }
  }
  __threadfence();
  e++; gsync(p.flags, p.gen, e);

  // ================= main scan: 2 barriers per step =================
  for (int t = 0; t < T_; t++){

    // ---------- PA ----------
    if (blk < 24){
      // XCD pairing (r11): (k, k+8) share h for h<8; heads 8..11 residual.
      int h, bh;
      if (blk < 16){ h = blk & 7; bh = blk >> 3; }
      else { int l2 = blk - 16; h = 8 + (l2 & 3); bh = l2 >> 2; }
      {
        int m = tid0 >> 3, j = tid0 & 7;      // 64 rows, 8 thr/row, 12 chunks ea
        int b = bh*32 + (m & 31);
        int st;
        if (m < 32){ int pt = p.ping[b*T_ + t]; st = pt - 1; if (st < 0) st = 0; if (st > T_-1) st = T_-1; }
        else st = t;
        const f4* src = (const f4*)(p.xB + ((size_t)(st*64 + b))*768);
        f4 d0,d1,d2,d3,d4,d5,d6,d7;
        cldx4_8(d0,d1,d2,d3,d4,d5,d6,d7,
                src+j,    src+j+ 8, src+j+16, src+j+24,
                src+j+32, src+j+40, src+j+48, src+j+56);
        aput16(As,768,m,j,    d0); aput16(As,768,m,j+ 8,d1);
        aput16(As,768,m,j+16, d2); aput16(As,768,m,j+24,d3);
        aput16(As,768,m,j+32, d4); aput16(As,768,m,j+40,d5);
        aput16(As,768,m,j+48, d6); aput16(As,768,m,j+56,d7);
        f4 e0,e1,e2,e3;
        cldx4_4(e0,e1,e2,e3, src+j+64, src+j+72, src+j+80, src+j+88);
        aput16(As,768,m,j+64, e0); aput16(As,768,m,j+72,e1);
        aput16(As,768,m,j+80, e2); aput16(As,768,m,j+88,e3);
      }
      __syncthreads();
      // M-split across wave-halves: wvL = slice group, mh2 = M-half
      const int wvL = wv & 3, mh2 = wv >> 2;
      f4 acc[3][2];
      #pragma unroll
      for (int i = 0; i < 3; i++)
        #pragma unroll
        for (int mtl = 0; mtl < 2; mtl++) acc[i][mtl] = f4{0.f,0.f,0.f,0.f};
      for (int kb = 0; kb < 24; kb++){
        short8 af[2];
        #pragma unroll
        for (int mtl = 0; mtl < 2; mtl++)
          af[mtl] = afrag(As, 768, (mh2*2 + mtl)*16 + c16, kb, q4);
        #pragma unroll
        for (int i = 0; i < 3; i++){
          short8 bf = *(const short8*)(p.Wqkv_s + ((size_t)((h*24 + kb)*12 + wvL*3 + i))*512 + lane*8);
          #pragma unroll
          for (int mtl = 0; mtl < 2; mtl++) acc[i][mtl] = mfma16(af[mtl], bf, acc[i][mtl]);
        }
      }
      #pragma unroll
      for (int i = 0; i < 3; i++){
        int nl = (wvL*3 + i)*16 + c16;
        float bias = (nl < 64) ? p.bq[h*64+nl] : (nl < 128 ? p.bk[h*64+nl-64] : p.bv[h*64+nl-128]);
        #pragma unroll
        for (int mtl = 0; mtl < 2; mtl++){
          int mt = mh2*2 + mtl;
          #pragma unroll
          for (int r = 0; r < 4; r++)
            qkvs[(mt*16 + q4*4 + r)*192 + nl] = f2b(acc[i][mtl][r] + bias);
        }
      }
      __syncthreads();
      for (int pi = 0; pi < 4; pi++){
        int bi = wv*4 + pi;                 // 32 bi over 8 waves
        const u16t* L = qkvs + bi*192;
        const u16t* R = qkvs + (32+bi)*192;
        float ql = b2f(L[lane]), kl = b2f(L[64+lane]), vl = b2f(L[128+lane]);
        float qr = b2f(R[lane]), kr = b2f(R[64+lane]), vr = b2f(R[128+lane]);
        float sll = wsum(ql*kl)*0.125f, slr = wsum(ql*kr)*0.125f;
        float srl = wsum(qr*kl)*0.125f, srr = wsum(qr*kr)*0.125f;
        float ml = fmaxf(sll, slr), mr = fmaxf(srl, srr);
        float ell = __expf(sll-ml), elr = __expf(slr-ml);
        float erl = __expf(srl-mr), err = __expf(srr-mr);
        float il = 1.0f/(ell+elr), ir = 1.0f/(erl+err);
        float cl = (ell*il)*vl + (elr*il)*vr;
        float cr = (erl*ir)*vl + (err*ir)*vr;
        float cl2 = __shfl_xor(cl, 1), cr2 = __shfl_xor(cr, 1);
        if (!(lane & 1)){
          int b = bh*32 + bi;
          cst32((u32t*)(p.ctxb + (size_t)b*1536 + h*64 + lane),
                (u32t)f2b(cl) | ((u32t)f2b(cl2) << 16));
          cst32((u32t*)(p.ctxb + (size_t)b*1536 + 768 + h*64 + lane),
                (u32t)f2b(cr) | ((u32t)f2b(cr2) << 16));
        }
      }
    } else {
      // gates: XCD pairing (24+n, 48+n) share ng=n
      const int local = blk - 24, mh = local / 24, ng = local % 24;
      const int b0 = mh*32;
      if (tid0 == 0) anyX = 0;
      __syncthreads();
      {
        int m = tid0 >> 4, j = tid0 & 15;    // 32 rows, 16 thr/row, 6+6 chunks
        int b = b0 + m;
        int pt = p.ping[b*T_ + t];
        bool cond = (pt > 0) && (t > 0);
        const f4* hsrc = (const f4*)(p.hB + (size_t)b*768);
        {
          f4 d0,d1,d2,d3,d4,d5;
          cldx4_6(d0,d1,d2,d3,d4,d5,
                  hsrc+j, hsrc+j+16, hsrc+j+32, hsrc+j+48, hsrc+j+64, hsrc+j+80);
          aput16(As,1536,m,j,    d0); aput16(As,1536,m,j+16,d1);
          aput16(As,1536,m,j+32, d2); aput16(As,1536,m,j+48,d3);
          aput16(As,1536,m,j+64, d4); aput16(As,1536,m,j+80,d5);
        }
        if (cond){
          #pragma unroll
          for (int i = 0; i < 6; i++) aput16(As,1536,m,96 + j + 16*i, f4{0.f,0.f,0.f,0.f});
        } else {
          if (j == 0) anyX = 1;
          const f4* xsrc = (const f4*)(p.xB + ((size_t)(t*64 + b))*768);
          f4 d0,d1,d2,d3,d4,d5;
          cldx4_6(d0,d1,d2,d3,d4,d5,
                  xsrc+j, xsrc+j+16, xsrc+j+32, xsrc+j+48, xsrc+j+64, xsrc+j+80);
          aput16(As,1536,m,96+j,    d0); aput16(As,1536,m,96+j+16,d1);
          aput16(As,1536,m,96+j+32, d2); aput16(As,1536,m,96+j+48,d3);
          aput16(As,1536,m,96+j+64, d4); aput16(As,1536,m,96+j+80,d5);
        }
      }
      __syncthreads();
      const int kbmax = anyX ? 48 : 24;
      // M-split: wvL = nt group, mtw = which 16-row half
      const int wvL = wv & 3, mtw = wv >> 2;
      f4 acc[2];
      #pragma unroll
      for (int i = 0; i < 2; i++) acc[i] = f4{0.f,0.f,0.f,0.f};
      for (int kb = 0; kb < kbmax; kb++){
        short8 af = afrag(As, 1536, mtw*16 + c16, kb, q4);
        #pragma unroll
        for (int i = 0; i < 2; i++){
          int nt = ng*8 + wvL*2 + i;
          short8 bf = *(const short8*)(p.Whhih_s + ((size_t)(kb*192 + nt))*512 + lane*8);
          acc[i] = mfma16(af, bf, acc[i]);
        }
      }
      #pragma unroll
      for (int i = 0; i < 2; i++){
        int n = (ng*8 + wvL*2 + i)*16 + c16;
        #pragma unroll
        for (int r = 0; r < 4; r++){
          int b = b0 + mtw*16 + q4*4 + r;
          cstf(p.gatesHX + (size_t)b*3072 + n, acc[i][r]);
        }
      }
    }
    e++; gsync(p.flags, p.gen, e);

    // ---------- PB ----------
    if (blk < 48){
      // cell: XCD pairing (k, k+24) share jjg=k
      const int mh = blk / 24, jjg = blk % 24;
      const int b0 = mh*32;
      {
        int m = tid0 >> 4, j = tid0 & 15;    // 32 rows, 16 thr/row, 12 chunks
        const f4* src = (const f4*)(p.ctxb + (size_t)(b0+m)*1536);
        f4 d0,d1,d2,d3,d4,d5,d6,d7;
        cldx4_8(d0,d1,d2,d3,d4,d5,d6,d7,
                src+j,    src+j+16, src+j+32, src+j+48,
                src+j+64, src+j+80, src+j+96, src+j+112);
        aput16(As,1536,m,j,     d0); aput16(As,1536,m,j+ 16,d1);
        aput16(As,1536,m,j+32,  d2); aput16(As,1536,m,j+ 48,d3);
        aput16(As,1536,m,j+64,  d4); aput16(As,1536,m,j+ 80,d5);
        aput16(As,1536,m,j+96,  d6); aput16(As,1536,m,j+112,d7);
        f4 e0,e1,e2,e3;
        cldx4_4(e0,e1,e2,e3, src+j+128, src+j+144, src+j+160, src+j+176);
        aput16(As,1536,m,j+128, e0); aput16(As,1536,m,j+144,e1);
        aput16(As,1536,m,j+160, e2); aput16(As,1536,m,j+176,e3);
      }
      __syncthreads();
      // K-split: kh = K-half; (jjt, mt) as r11 for low waves
      const int jjt = jjg*2 + (wv & 1), mt = (wv >> 1) & 1, kh = wv >> 2;
      const int jj = jjt*16 + c16;
      float gx[16];
      if (kh == 0){
        const float* a[16];
        #pragma unroll
        for (int r = 0; r < 4; r++){
          int b = b0 + mt*16 + q4*4 + r;
          size_t g0 = (size_t)b*3072 + jj;
          a[r*4+0] = p.gatesHX + g0;        a[r*4+1] = p.gatesHX + g0 + 768;
          a[r*4+2] = p.gatesHX + g0 + 1536; a[r*4+3] = p.gatesHX + g0 + 2304;
        }
        cldd8(gx[0],gx[1],gx[2],gx[3],gx[4],gx[5],gx[6],gx[7],
              a[0],a[1],a[2],a[3],a[4],a[5],a[6],a[7]);
        cldd8(gx[8],gx[9],gx[10],gx[11],gx[12],gx[13],gx[14],gx[15],
              a[8],a[9],a[10],a[11],a[12],a[13],a[14],a[15]);
      }
      f4 acc[4];
      #pragma unroll
      for (int g = 0; g < 4; g++) acc[g] = f4{0.f,0.f,0.f,0.f};
      for (int kb = kh*24; kb < kh*24 + 24; kb++){
        short8 af = afrag(As, 1536, mt*16 + c16, kb, q4);
        #pragma unroll
        for (int g = 0; g < 4; g++){
          short8 bf = *(const short8*)(p.Wcomb_s + ((size_t)(kb*192 + g*48 + jjt))*512 + lane*8);
          acc[g] = mfma16(af, bf, acc[g]);
        }
      }
      if (kh == 1){
        #pragma unroll
        for (int g = 0; g < 4; g++)
          #pragma unroll
          for (int r = 0; r < 4; r++)
            red[wv & 3][lane][g*4 + r] = acc[g][r];
      }
      __syncthreads();
      if (kh == 0){
        #pragma unroll
        for (int g = 0; g < 4; g++)
          #pragma unroll
          for (int r = 0; r < 4; r++)
            acc[g][r] += red[wv][lane][g*4 + r];
        float bfw[4];
        #pragma unroll
        for (int g = 0; g < 4; g++) bfw[g] = p.bfW[g*768 + jj];
        #pragma unroll
        for (int r = 0; r < 4; r++){
          int b = b0 + mt*16 + q4*4 + r;
          int pt = p.ping[b*T_ + t];
          bool cond = (pt > 0) && (t > 0);
          size_t g0 = (size_t)b*3072 + jj;
          float gi = p.base[g0]      + gx[r*4+0];
          float gf = p.base[g0+768]  + gx[r*4+1];
          float gg = p.base[g0+1536] + gx[r*4+2];
          float go = p.base[g0+2304] + gx[r*4+3];
          if (cond){
            gi += acc[0][r] + bfw[0]; gf += acc[1][r] + bfw[1];
            gg += acc[2][r] + bfw[2]; go += acc[3][r] + bfw[3];
          }
          float co = p.cbuf[b*768 + jj];
          float cn = sigm(gf)*co + sigm(gi)*tanh_(gg);
          float hh = sigm(go)*tanh_(cn);
          p.out[((size_t)(t*64 + b))*768 + jj] = hh;
          p.cbuf[b*768 + jj] = cn;
          float hp = __shfl_xor(hh, 1);
          if (!(c16 & 1))
            cst32((u32t*)(p.hB + (size_t)b*768 + jj), (u32t)f2b(hh) | ((u32t)f2b(hp) << 16));
          if (t == T_-1){
            p.out[HALL + b*768 + jj] = hh;
            p.out[HALL + 49152 + b*768 + jj] = cn;
          }
        }
      }
    } else {
      // fuse: pairing (48+k, 56+k) for ng<8 (partial)
      const int local = blk - 48;
      int ng, mh;
      if (local < 16){ ng = local & 7; mh = local >> 3; }
      else { int l2 = local - 16; ng = 8 + (l2 & 3); mh = l2 >> 2; }
      const int b0 = mh*32;
      {
        int m = tid0 >> 4, j = tid0 & 15;
        const f4* src = (const f4*)(p.ctxb + (size_t)(b0+m)*1536);
        f4 d0,d1,d2,d3,d4,d5,d6,d7;
        cldx4_8(d0,d1,d2,d3,d4,d5,d6,d7,
                src+j,    src+j+16, src+j+32, src+j+48,
                src+j+64, src+j+80, src+j+96, src+j+112);
        aput16(As,1536,m,j,     d0); aput16(As,1536,m,j+ 16,d1);
        aput16(As,1536,m,j+32,  d2); aput16(As,1536,m,j+ 48,d3);
        aput16(As,1536,m,j+64,  d4); aput16(As,1536,m,j+ 80,d5);
        aput16(As,1536,m,j+96,  d6); aput16(As,1536,m,j+112,d7);
        f4 e0,e1,e2,e3;
        cldx4_4(e0,e1,e2,e3, src+j+128, src+j+144, src+j+160, src+j+176);
        aput16(As,1536,m,j+128, e0); aput16(As,1536,m,j+144,e1);
        aput16(As,1536,m,j+160, e2); aput16(As,1536,m,j+176,e3);
      }
      __syncthreads();
      const int wvL = wv & 3, kh = wv >> 2;
      const int nt = ng*4 + wvL;
      f4 acc[2];
      #pragma unroll
      for (int mt = 0; mt < 2; mt++) acc[mt] = f4{0.f,0.f,0.f,0.f};
      for (int kb = kh*24; kb < kh*24 + 24; kb++){
        short8 bf = *(const short8*)(p.Wfuse_s + ((size_t)(kb*48 + nt))*512 + lane*8);
        #pragma unroll
        for (int mt = 0; mt < 2; mt++){
          short8 af = afrag(As, 1536, mt*16 + c16, kb, q4);
          acc[mt] = mfma16(af, bf, acc[mt]);
        }
      }
      if (kh == 1){
        #pragma unroll
        for (int mt = 0; mt < 2; mt++)
          #pragma unroll
          for (int r = 0; r < 4; r++)
            red[wvL][lane][mt*4 + r] = acc[mt][r];
      }
      __syncthreads();
      if (kh == 0){
        #pragma unroll
        for (int mt = 0; mt < 2; mt++)
          #pragma unroll
          for (int r = 0; r < 4; r++)
            acc[mt][r] += red[wv][lane][mt*4 + r];
        const int n = nt*16 + c16;
        const float bias = p.bfuse[n];
        #pragma unroll
        for (int mt = 0; mt < 2; mt++)
          #pragma unroll
          for (int r = 0; r < 4; r++){
            int b = b0 + mt*16 + q4*4 + r;
            int pt = p.ping[b*T_ + t];
            float v = acc[mt][r] + bias;
            float v2 = __shfl_xor(v, 1);
            if ((pt > 0) && (t > 0) && !(c16 & 1))
              cst32((u32t*)(p.xB + ((size_t)(t*64 + b))*768 + n),
                    (u32t)f2b(v) | ((u32t)f2b(v2) << 16));
          }
      }
    }
    e++; gsync(p.flags, p.gen, e);
  }
}

extern "C" void kernel_launch(void* const* d_in, const int* in_sizes, int n_in,
                              void* d_out, int out_size, void* d_ws, size_t ws_size,
                              hipStream_t stream)
{
  (void)in_sizes; (void)n_in; (void)out_size; (void)ws_size;
  char* ws = (char*)d_ws;
  size_t off = 0;
  auto take = [&](size_t bytes)->void*{
    void* ptr = ws + off;
    off += (bytes + 255) & ~(size_t)255;
    return ptr;
  };

  Params p;
  p.question = (const float*)d_in[0];
  p.answer   = (const float*)d_in[1];
  p.x        = (const float*)d_in[2];
  p.ping     = (const int*)d_in[3];
  p.h0  = (const float*)d_in[4];  p.c0  = (const float*)d_in[5];
  p.Wqh = (const float*)d_in[6];  p.bqh = (const float*)d_in[7];
  p.Wah = (const float*)d_in[8];  p.bah = (const float*)d_in[9];
  p.Wih = (const float*)d_in[10]; p.bih = (const float*)d_in[11];
  p.Whh = (const float*)d_in[12]; p.bhh = (const float*)d_in[13];
  p.Wq  = (const float*)d_in[14]; p.bq  = (const float*)d_in[15];
  p.Wk  = (const float*)d_in[16]; p.bk  = (const float*)d_in[17];
  p.Wv  = (const float*)d_in[18]; p.bv  = (const float*)d_in[19];
  p.Wfuse = (const float*)d_in[20]; p.bfuse = (const float*)d_in[21];
  p.out = (float*)d_out;

  u32t* sync = (u32t*)take(16384);
  p.flags = sync;
  p.gen   = sync + 3072;

  p.Wqkv_s   = (u16t*)take((size_t)221184*16);
  p.Whhih_s  = (u16t*)take((size_t)589824*16);
  p.Wfuse_s  = (u16t*)take((size_t)147456*16);
  p.Wcomb_s  = (u16t*)take((size_t)589824*16);
  p.Wfuse_bf = (u16t*)take((size_t)1536*768*2);
  p.base     = (float*)take((size_t)64*3072*4);
  p.gatesHX  = (float*)take((size_t)64*3072*4);
  p.ctxb     = (u16t*)take((size_t)64*1536*2);
  p.hB       = (u16t*)take((size_t)64*768*2);
  p.cbuf     = (float*)take((size_t)64*768*4);
  p.bfW      = (float*)take((size_t)3072*4);
  p.xB       = (u16t*)take((size_t)12582912*2);

  hipFuncSetAttribute(reinterpret_cast<const void*>(sqac_kernel),
                      hipFuncAttributeMaxDynamicSharedMemorySize, 98304);
  hipMemsetAsync(sync, 0, 16384, stream);
  hipLaunchKernelGGL(sqac_kernel, dim3(NBLK), dim3(NTHR), 98304, stream, p);
}

// Round 10
// 17731.764 us; speedup vs baseline: 1.3771x; 1.3771x over previous
//
#include <hip/hip_runtime.h>
#include <cstdint>
#include <cstddef>

// SQACILSTM round 14: revert to r11 (17.1ms, FETCH 1.25e6 KB - best known)
// after r13's falsifiable check failed: 512-thread blocks broke the XCD
// pairing (FETCH 6x back to exactly the unpaired 28.5 MB/step level) ->
// the dispatcher's blk->XCD map differs for 512-thr workgroups. The
// 72 x 256 shape is load-bearing; TLP-via-shape-change is dead (3 tries).
// This round: shape-preserving serial-latency cuts only:
// (A) wider waitcnt batches: staging 3x8 -> 2x12 loads (PA/PB/fuse),
//     gates 8+4 -> 1x12, gx gather 2x8 -> 1x16 dwords. Removes 4-5 serial
//     LLC round trips per step.
// (B) explicit B-slice prefetch (kb+1) in all four MFMA loops.
// Predicted: FETCH ~1.25e6 (restoration signal), dur 17.1 -> ~15-16.5ms.

#define T_   256
#define B_   64
#define NBLK 72
#define NTHR 256
#define GRIDTH (NBLK*NTHR)
#define HALL 12582912   // 256*64*768

typedef __attribute__((ext_vector_type(8))) short short8;
typedef __attribute__((ext_vector_type(4))) float f4;
typedef unsigned long long u64t;
typedef unsigned short u16t;
typedef unsigned int u32t;

struct Params {
  const float* question; const float* answer; const float* x; const int* ping;
  const float* h0; const float* c0;
  const float* Wqh; const float* bqh; const float* Wah; const float* bah;
  const float* Wih; const float* bih; const float* Whh; const float* bhh;
  const float* Wq;  const float* bq;  const float* Wk;  const float* bk;
  const float* Wv;  const float* bv;  const float* Wfuse; const float* bfuse;
  float* out;
  u32t* flags; u32t* gen;
  u16t* Wqkv_s; u16t* Whhih_s; u16t* Wfuse_s; u16t* Wcomb_s; u16t* Wfuse_bf;
  float* base; float* gatesHX; u16t* ctxb; u16t* hB; float* cbuf; float* bfW;
  u16t* xB;
};

__device__ __forceinline__ u16t f2b(float f){
  union { float f; u32t u; } a; a.f = f;
  u32t u = a.u;
  u32t r = u + 0x7FFFu + ((u >> 16) & 1u);
  return (u16t)(r >> 16);
}
__device__ __forceinline__ float b2f(u16t u){
  union { u32t u; float f; } a; a.u = ((u32t)u) << 16; return a.f;
}
__device__ __forceinline__ u64t pack4f(float a, float b, float c, float d){
  return (u64t)f2b(a) | ((u64t)f2b(b)<<16) | ((u64t)f2b(c)<<32) | ((u64t)f2b(d)<<48);
}
__device__ __forceinline__ float sigm(float x){ return 1.0f/(1.0f+__expf(-x)); }
__device__ __forceinline__ float tanh_(float x){ return 2.0f/(1.0f+__expf(-2.0f*x)) - 1.0f; }
__device__ __forceinline__ f4 mfma16(short8 a, short8 b, f4 c){
  return __builtin_amdgcn_mfma_f32_16x16x32_bf16(a, b, c, 0, 0, 0);
}
__device__ __forceinline__ float wsum(float x){
  #pragma unroll
  for (int off = 32; off > 0; off >>= 1) x += __shfl_xor(x, off, 64);
  return x;
}

// ---- batched coherent loads (LLC / sc0 sc1), one waitcnt per batch ----
__device__ __forceinline__ void cldx4_12(
  f4&d0,f4&d1,f4&d2,f4&d3,f4&d4,f4&d5,f4&d6,f4&d7,f4&d8,f4&d9,f4&d10,f4&d11,
  const void*a0,const void*a1,const void*a2,const void*a3,
  const void*a4,const void*a5,const void*a6,const void*a7,
  const void*a8,const void*a9,const void*a10,const void*a11){
  asm volatile(
    "global_load_dwordx4 %0, %12, off sc0 sc1\n\t"
    "global_load_dwordx4 %1, %13, off sc0 sc1\n\t"
    "global_load_dwordx4 %2, %14, off sc0 sc1\n\t"
    "global_load_dwordx4 %3, %15, off sc0 sc1\n\t"
    "global_load_dwordx4 %4, %16, off sc0 sc1\n\t"
    "global_load_dwordx4 %5, %17, off sc0 sc1\n\t"
    "global_load_dwordx4 %6, %18, off sc0 sc1\n\t"
    "global_load_dwordx4 %7, %19, off sc0 sc1\n\t"
    "global_load_dwordx4 %8, %20, off sc0 sc1\n\t"
    "global_load_dwordx4 %9, %21, off sc0 sc1\n\t"
    "global_load_dwordx4 %10, %22, off sc0 sc1\n\t"
    "global_load_dwordx4 %11, %23, off sc0 sc1\n\t"
    "s_waitcnt vmcnt(0)"
    : "=&v"(d0),"=&v"(d1),"=&v"(d2),"=&v"(d3),"=&v"(d4),"=&v"(d5),
      "=&v"(d6),"=&v"(d7),"=&v"(d8),"=&v"(d9),"=&v"(d10),"=&v"(d11)
    : "v"(a0),"v"(a1),"v"(a2),"v"(a3),"v"(a4),"v"(a5),
      "v"(a6),"v"(a7),"v"(a8),"v"(a9),"v"(a10),"v"(a11));
}
__device__ __forceinline__ void cldd16(float* g,
  const float*a0,const float*a1,const float*a2,const float*a3,
  const float*a4,const float*a5,const float*a6,const float*a7,
  const float*a8,const float*a9,const float*a10,const float*a11,
  const float*a12,const float*a13,const float*a14,const float*a15){
  asm volatile(
    "global_load_dword %0, %16, off sc0 sc1\n\t"
    "global_load_dword %1, %17, off sc0 sc1\n\t"
    "global_load_dword %2, %18, off sc0 sc1\n\t"
    "global_load_dword %3, %19, off sc0 sc1\n\t"
    "global_load_dword %4, %20, off sc0 sc1\n\t"
    "global_load_dword %5, %21, off sc0 sc1\n\t"
    "global_load_dword %6, %22, off sc0 sc1\n\t"
    "global_load_dword %7, %23, off sc0 sc1\n\t"
    "global_load_dword %8, %24, off sc0 sc1\n\t"
    "global_load_dword %9, %25, off sc0 sc1\n\t"
    "global_load_dword %10, %26, off sc0 sc1\n\t"
    "global_load_dword %11, %27, off sc0 sc1\n\t"
    "global_load_dword %12, %28, off sc0 sc1\n\t"
    "global_load_dword %13, %29, off sc0 sc1\n\t"
    "global_load_dword %14, %30, off sc0 sc1\n\t"
    "global_load_dword %15, %31, off sc0 sc1\n\t"
    "s_waitcnt vmcnt(0)"
    : "=&v"(g[0]),"=&v"(g[1]),"=&v"(g[2]),"=&v"(g[3]),
      "=&v"(g[4]),"=&v"(g[5]),"=&v"(g[6]),"=&v"(g[7]),
      "=&v"(g[8]),"=&v"(g[9]),"=&v"(g[10]),"=&v"(g[11]),
      "=&v"(g[12]),"=&v"(g[13]),"=&v"(g[14]),"=&v"(g[15])
    : "v"(a0),"v"(a1),"v"(a2),"v"(a3),"v"(a4),"v"(a5),"v"(a6),"v"(a7),
      "v"(a8),"v"(a9),"v"(a10),"v"(a11),"v"(a12),"v"(a13),"v"(a14),"v"(a15));
}

// ---- coherent stores (fire-and-forget; drained by barrier's vmcnt wait) ----
__device__ __forceinline__ void cstf(float* p, float v){
  __hip_atomic_store(p, v, __ATOMIC_RELAXED, __HIP_MEMORY_SCOPE_AGENT);
}
__device__ __forceinline__ void cst32(u32t* p, u32t v){
  __hip_atomic_store(p, v, __ATOMIC_RELAXED, __HIP_MEMORY_SCOPE_AGENT);
}

// ---- LDS A-tile, XOR-swizzled 16B chunks ----
__device__ __forceinline__ void aput16(u16t* As, int rowu16, int m, int cc, f4 v){
  int slot = (cc & ~7) | ((cc ^ m) & 7);
  *(f4*)(As + m*rowu16 + slot*8) = v;
}
__device__ __forceinline__ short8 afrag(const u16t* As, int rowu16, int m, int kb, int q4){
  int c = kb*4 + q4;
  int phys = (c & ~7) | ((c ^ m) & 7);
  return *(const short8*)(As + m*rowu16 + phys*8);
}

// ---- grid barrier: relaxed agent atomics only, no cache invalidation ----
__device__ __forceinline__ void gsync(u32t* flags, u32t* gen, u32t e){
  asm volatile("s_waitcnt vmcnt(0) lgkmcnt(0)" ::: "memory");
  __syncthreads();
  if (blockIdx.x == 0){
    if (threadIdx.x > 0 && threadIdx.x < NBLK){
      while (__hip_atomic_load(flags + threadIdx.x*32, __ATOMIC_RELAXED, __HIP_MEMORY_SCOPE_AGENT) < e) ;
    }
    __syncthreads();
    if (threadIdx.x == 0)
      __hip_atomic_store(gen, e, __ATOMIC_RELAXED, __HIP_MEMORY_SCOPE_AGENT);
  } else {
    if (threadIdx.x == 0){
      __hip_atomic_store(flags + blockIdx.x*32, e, __ATOMIC_RELAXED, __HIP_MEMORY_SCOPE_AGENT);
      while (__hip_atomic_load(gen, __ATOMIC_RELAXED, __HIP_MEMORY_SCOPE_AGENT) < e) ;
    }
  }
  __builtin_amdgcn_fence(__ATOMIC_ACQUIRE, "workgroup");
  __syncthreads();
}

__launch_bounds__(NTHR, 1)
__global__ void sqac_kernel(Params p){
  extern __shared__ u16t As[];           // 96KB dynamic A-tile
  __shared__ u16t qkvs[64*192];          // 24KB qkv exchange
  __shared__ int anyX;
  const int tid0 = threadIdx.x;
  const int blk  = blockIdx.x;
  const int tid  = blk*NTHR + tid0;
  const int lane = tid0 & 63;
  const int wv   = tid0 >> 6;
  const int c16  = lane & 15, q4 = lane >> 4;
  u32t e = 0;

  // ================= P0 stage 1: conversions / swizzles / base =================
  {
    for (int idx = tid; idx < 12288; idx += GRIDTH){
      f4 h = *(const f4*)(p.h0 + idx*4);
      *(u64t*)(p.hB + idx*4) = pack4f(h.x, h.y, h.z, h.w);
      *(f4*)(p.cbuf + idx*4) = *(const f4*)(p.c0 + idx*4);
    }
    // x -> bf16 mirror (all consumers convert to bf16 anyway; bit-identical)
    for (int idx = tid; idx < 3145728; idx += GRIDTH){
      f4 v = *(const f4*)(p.x + (size_t)idx*4);
      *(u64t*)(p.xB + (size_t)idx*4) = pack4f(v.x, v.y, v.z, v.w);
    }
    for (int idx = tid; idx < 221184; idx += GRIDTH){
      int l = idx & 63, g2 = idx >> 6;
      int ntl = g2 % 12, kb = (g2/12) % 24, h = g2/288;
      int k0 = kb*32 + ((l>>4)<<3);
      int nl = ntl*16 + (l&15);
      const float* s; int col;
      if (nl < 64){ s = p.Wq; col = h*64 + nl; }
      else if (nl < 128){ s = p.Wk; col = h*64 + nl - 64; }
      else { s = p.Wv; col = h*64 + nl - 128; }
      union { u16t a[8]; short8 v; } t8;
      #pragma unroll
      for (int j = 0; j < 8; j++) t8.a[j] = f2b(s[(size_t)(k0+j)*768 + col]);
      *(short8*)(p.Wqkv_s + (size_t)idx*8) = t8.v;
    }
    for (int idx = tid; idx < 589824; idx += GRIDTH){
      int l = idx & 63, g2 = idx >> 6;
      int nb = g2 % 192, kb2 = g2 / 192;
      int n  = nb*16 + (l&15);
      int kl = (kb2 % 24)*32 + ((l>>4)<<3);
      const float* s = (kb2 < 24) ? p.Whh : p.Wih;
      union { u16t a[8]; short8 v; } t8;
      #pragma unroll
      for (int j = 0; j < 8; j++) t8.a[j] = f2b(s[(size_t)(kl+j)*3072 + n]);
      *(short8*)(p.Whhih_s + (size_t)idx*8) = t8.v;
    }
    for (int idx = tid; idx < 147456; idx += GRIDTH){
      int l = idx & 63, g2 = idx >> 6;
      int nb = g2 % 48, kb = g2 / 48;
      int n  = nb*16 + (l&15);
      int k0 = kb*32 + ((l>>4)<<3);
      union { u16t a[8]; short8 v; } t8;
      #pragma unroll
      for (int j = 0; j < 8; j++) t8.a[j] = f2b(p.Wfuse[(size_t)(k0+j)*768 + n]);
      *(short8*)(p.Wfuse_s + (size_t)idx*8) = t8.v;
    }
    for (int idx = tid; idx < 294912; idx += GRIDTH){
      f4 v = *(const f4*)(p.Wfuse + idx*4);
      *(u64t*)(p.Wfuse_bf + idx*4) = pack4f(v.x, v.y, v.z, v.w);
    }
    for (int w = tid; w < 24576; w += GRIDTH){
      int bg = w / 3072, n = w - bg*3072;
      float acc[8];
      #pragma unroll
      for (int bi = 0; bi < 8; bi++) acc[bi] = 0.f;
      for (int k = 0; k < 768; k++){
        float wq = p.Wqh[(size_t)k*3072 + n];
        float wa = p.Wah[(size_t)k*3072 + n];
        #pragma unroll
        for (int bi = 0; bi < 8; bi++){
          int b = bg*8 + bi;
          acc[bi] += p.question[b*768 + k]*wq + p.answer[b*768 + k]*wa;
        }
      }
      float bias = p.bqh[n] + p.bah[n] + p.bih[n] + p.bhh[n];
      #pragma unroll
      for (int bi = 0; bi < 8; bi++)
        p.base[(size_t)(bg*8+bi)*3072 + n] = acc[bi] + bias;
    }
    for (int n = tid; n < 3072; n += GRIDTH){
      float a = 0.f;
      for (int k = 0; k < 768; k++) a += p.bfuse[k]*p.Wih[(size_t)k*3072 + n];
      p.bfW[n] = a;
    }
  }
  __threadfence();
  e++; gsync(p.flags, p.gen, e);

  // ================= P0 stage 2: Wcomb = Wfuse @ Wih (MFMA) =================
  {
    int w = tid >> 6;
    int mt = w % 96, ntg = w / 96;
    for (int nt = ntg*64; nt < ntg*64 + 64; nt++){
      f4 acc = {0.f,0.f,0.f,0.f};
      for (int kb = 0; kb < 24; kb++){
        short8 af = *(const short8*)(p.Wfuse_bf + (size_t)(mt*16 + c16)*768 + kb*32 + q4*8);
        short8 bf = *(const short8*)(p.Whhih_s + ((size_t)((24+kb)*192 + nt))*512 + lane*8);
        acc = mfma16(af, bf, acc);
      }
      #pragma unroll
      for (int r = 0; r < 4; r++){
        int k1 = mt*16 + q4*4 + r;
        p.Wcomb_s[((size_t)((k1>>5)*192 + nt))*512 + (size_t)((((k1>>3)&3)*16 + c16)*8 + (k1&7))] = f2b(acc[r]);
      }
    }
  }
  __threadfence();
  e++; gsync(p.flags, p.gen, e);

  // ================= main scan: 2 barriers per step =================
  for (int t = 0; t < T_; t++){

    // ---------- PA ----------
    if (blk < 24){
      // XCD pairing (r11): (k, k+8) share h for h<8; heads 8..11 residual.
      int h, bh;
      if (blk < 16){ h = blk & 7; bh = blk >> 3; }
      else { int l2 = blk - 16; h = 8 + (l2 & 3); bh = l2 >> 2; }
      {
        int m = tid0 >> 2, j = tid0 & 3;      // 64 rows, 4 thr/row, 96 chunks/row
        int b = bh*32 + (m & 31);
        int st;
        if (m < 32){ int pt = p.ping[b*T_ + t]; st = pt - 1; if (st < 0) st = 0; if (st > T_-1) st = T_-1; }
        else st = t;
        const f4* src = (const f4*)(p.xB + ((size_t)(st*64 + b))*768);
        #pragma unroll
        for (int g = 0; g < 2; g++){
          f4 d0,d1,d2,d3,d4,d5,d6,d7,d8,d9,d10,d11;
          int c0 = j + 48*g;                  // cc = c0 + 4i, i=0..11
          cldx4_12(d0,d1,d2,d3,d4,d5,d6,d7,d8,d9,d10,d11,
                   src+c0,    src+c0+ 4, src+c0+ 8, src+c0+12,
                   src+c0+16, src+c0+20, src+c0+24, src+c0+28,
                   src+c0+32, src+c0+36, src+c0+40, src+c0+44);
          aput16(As,768,m,c0,    d0);  aput16(As,768,m,c0+ 4,d1);
          aput16(As,768,m,c0+ 8, d2);  aput16(As,768,m,c0+12,d3);
          aput16(As,768,m,c0+16, d4);  aput16(As,768,m,c0+20,d5);
          aput16(As,768,m,c0+24, d6);  aput16(As,768,m,c0+28,d7);
          aput16(As,768,m,c0+32, d8);  aput16(As,768,m,c0+36,d9);
          aput16(As,768,m,c0+40, d10); aput16(As,768,m,c0+44,d11);
        }
      }
      __syncthreads();
      f4 acc[3][4];
      #pragma unroll
      for (int i = 0; i < 3; i++)
        #pragma unroll
        for (int mt = 0; mt < 4; mt++) acc[i][mt] = f4{0.f,0.f,0.f,0.f};
      // B-prefetch: load kb+1's slices before issuing kb's MFMAs
      short8 bfc[3];
      #pragma unroll
      for (int i = 0; i < 3; i++)
        bfc[i] = *(const short8*)(p.Wqkv_s + ((size_t)((h*24 + 0)*12 + wv*3 + i))*512 + lane*8);
      for (int kb = 0; kb < 24; kb++){
        int kbn = (kb < 23) ? kb + 1 : kb;
        short8 bfn[3];
        #pragma unroll
        for (int i = 0; i < 3; i++)
          bfn[i] = *(const short8*)(p.Wqkv_s + ((size_t)((h*24 + kbn)*12 + wv*3 + i))*512 + lane*8);
        short8 af[4];
        #pragma unroll
        for (int mt = 0; mt < 4; mt++) af[mt] = afrag(As, 768, mt*16 + c16, kb, q4);
        #pragma unroll
        for (int i = 0; i < 3; i++)
          #pragma unroll
          for (int mt = 0; mt < 4; mt++) acc[i][mt] = mfma16(af[mt], bfc[i], acc[i][mt]);
        #pragma unroll
        for (int i = 0; i < 3; i++) bfc[i] = bfn[i];
      }
      #pragma unroll
      for (int i = 0; i < 3; i++){
        int nl = (wv*3 + i)*16 + c16;
        float bias = (nl < 64) ? p.bq[h*64+nl] : (nl < 128 ? p.bk[h*64+nl-64] : p.bv[h*64+nl-128]);
        #pragma unroll
        for (int mt = 0; mt < 4; mt++)
          #pragma unroll
          for (int r = 0; r < 4; r++)
            qkvs[(mt*16 + q4*4 + r)*192 + nl] = f2b(acc[i][mt][r] + bias);
      }
      __syncthreads();
      for (int pi = 0; pi < 8; pi++){
        int bi = wv*8 + pi;
        const u16t* L = qkvs + bi*192;
        const u16t* R = qkvs + (32+bi)*192;
        float ql = b2f(L[lane]), kl = b2f(L[64+lane]), vl = b2f(L[128+lane]);
        float qr = b2f(R[lane]), kr = b2f(R[64+lane]), vr = b2f(R[128+lane]);
        float sll = wsum(ql*kl)*0.125f, slr = wsum(ql*kr)*0.125f;
        float srl = wsum(qr*kl)*0.125f, srr = wsum(qr*kr)*0.125f;
        float ml = fmaxf(sll, slr), mr = fmaxf(srl, srr);
        float ell = __expf(sll-ml), elr = __expf(slr-ml);
        float erl = __expf(srl-mr), err = __expf(srr-mr);
        float il = 1.0f/(ell+elr), ir = 1.0f/(erl+err);
        float cl = (ell*il)*vl + (elr*il)*vr;
        float cr = (erl*ir)*vl + (err*ir)*vr;
        float cl2 = __shfl_xor(cl, 1), cr2 = __shfl_xor(cr, 1);
        if (!(lane & 1)){
          int b = bh*32 + bi;
          cst32((u32t*)(p.ctxb + (size_t)b*1536 + h*64 + lane),
                (u32t)f2b(cl) | ((u32t)f2b(cl2) << 16));
          cst32((u32t*)(p.ctxb + (size_t)b*1536 + 768 + h*64 + lane),
                (u32t)f2b(cr) | ((u32t)f2b(cr2) << 16));
        }
      }
    } else {
      // gates: XCD pairing (24+n, 48+n) share ng=n
      const int local = blk - 24, mh = local / 24, ng = local % 24;
      const int b0 = mh*32;
      if (tid0 == 0) anyX = 0;
      __syncthreads();
      {
        int m = tid0 >> 3, j = tid0 & 7;     // 32 rows, 8 thr/row, 96+96 chunks
        int b = b0 + m;
        int pt = p.ping[b*T_ + t];
        bool cond = (pt > 0) && (t > 0);
        const f4* hsrc = (const f4*)(p.hB + (size_t)b*768);
        {
          f4 d0,d1,d2,d3,d4,d5,d6,d7,d8,d9,d10,d11;
          cldx4_12(d0,d1,d2,d3,d4,d5,d6,d7,d8,d9,d10,d11,
                   hsrc+j,    hsrc+j+ 8, hsrc+j+16, hsrc+j+24,
                   hsrc+j+32, hsrc+j+40, hsrc+j+48, hsrc+j+56,
                   hsrc+j+64, hsrc+j+72, hsrc+j+80, hsrc+j+88);
          aput16(As,1536,m,j,    d0);  aput16(As,1536,m,j+ 8,d1);
          aput16(As,1536,m,j+16, d2);  aput16(As,1536,m,j+24,d3);
          aput16(As,1536,m,j+32, d4);  aput16(As,1536,m,j+40,d5);
          aput16(As,1536,m,j+48, d6);  aput16(As,1536,m,j+56,d7);
          aput16(As,1536,m,j+64, d8);  aput16(As,1536,m,j+72,d9);
          aput16(As,1536,m,j+80, d10); aput16(As,1536,m,j+88,d11);
        }
        if (cond){
          #pragma unroll
          for (int i = 0; i < 12; i++) aput16(As,1536,m,96 + j + 8*i, f4{0.f,0.f,0.f,0.f});
        } else {
          if (j == 0) anyX = 1;
          const f4* xsrc = (const f4*)(p.xB + ((size_t)(t*64 + b))*768);
          f4 d0,d1,d2,d3,d4,d5,d6,d7,d8,d9,d10,d11;
          cldx4_12(d0,d1,d2,d3,d4,d5,d6,d7,d8,d9,d10,d11,
                   xsrc+j,    xsrc+j+ 8, xsrc+j+16, xsrc+j+24,
                   xsrc+j+32, xsrc+j+40, xsrc+j+48, xsrc+j+56,
                   xsrc+j+64, xsrc+j+72, xsrc+j+80, xsrc+j+88);
          aput16(As,1536,m,96+j,    d0);  aput16(As,1536,m,96+j+ 8,d1);
          aput16(As,1536,m,96+j+16, d2);  aput16(As,1536,m,96+j+24,d3);
          aput16(As,1536,m,96+j+32, d4);  aput16(As,1536,m,96+j+40,d5);
          aput16(As,1536,m,96+j+48, d6);  aput16(As,1536,m,96+j+56,d7);
          aput16(As,1536,m,96+j+64, d8);  aput16(As,1536,m,96+j+72,d9);
          aput16(As,1536,m,96+j+80, d10); aput16(As,1536,m,96+j+88,d11);
        }
      }
      __syncthreads();
      const int kbmax = anyX ? 48 : 24;     // x-half is all zeros when !anyX
      f4 acc[2][2];
      #pragma unroll
      for (int i = 0; i < 2; i++)
        #pragma unroll
        for (int mt = 0; mt < 2; mt++) acc[i][mt] = f4{0.f,0.f,0.f,0.f};
      short8 bfc[2];
      #pragma unroll
      for (int i = 0; i < 2; i++){
        int nt = ng*8 + wv*2 + i;
        bfc[i] = *(const short8*)(p.Whhih_s + ((size_t)(0*192 + nt))*512 + lane*8);
      }
      for (int kb = 0; kb < kbmax; kb++){
        int kbn = (kb + 1 < kbmax) ? kb + 1 : kb;
        short8 bfn[2];
        #pragma unroll
        for (int i = 0; i < 2; i++){
          int nt = ng*8 + wv*2 + i;
          bfn[i] = *(const short8*)(p.Whhih_s + ((size_t)(kbn*192 + nt))*512 + lane*8);
        }
        short8 af[2];
        #pragma unroll
        for (int mt = 0; mt < 2; mt++) af[mt] = afrag(As, 1536, mt*16 + c16, kb, q4);
        #pragma unroll
        for (int i = 0; i < 2; i++)
          #pragma unroll
          for (int mt = 0; mt < 2; mt++) acc[i][mt] = mfma16(af[mt], bfc[i], acc[i][mt]);
        #pragma unroll
        for (int i = 0; i < 2; i++) bfc[i] = bfn[i];
      }
      #pragma unroll
      for (int i = 0; i < 2; i++){
        int n = (ng*8 + wv*2 + i)*16 + c16;
        #pragma unroll
        for (int mt = 0; mt < 2; mt++)
          #pragma unroll
          for (int r = 0; r < 4; r++){
            int b = b0 + mt*16 + q4*4 + r;
            cstf(p.gatesHX + (size_t)b*3072 + n, acc[i][mt][r]);
          }
      }
    }
    e++; gsync(p.flags, p.gen, e);

    // ---------- PB ----------
    if (blk < 48){
      // cell: XCD pairing (k, k+24) share jjg=k
      const int mh = blk / 24, jjg = blk % 24;
      const int b0 = mh*32;
      {
        int m = tid0 >> 3, j = tid0 & 7;     // 32 rows, 8 thr/row, 192 chunks/row
        const f4* src = (const f4*)(p.ctxb + (size_t)(b0+m)*1536);
        #pragma unroll
        for (int g = 0; g < 2; g++){
          f4 d0,d1,d2,d3,d4,d5,d6,d7,d8,d9,d10,d11;
          int c0 = j + 96*g;                  // cc = c0 + 8i, i=0..11
          cldx4_12(d0,d1,d2,d3,d4,d5,d6,d7,d8,d9,d10,d11,
                   src+c0,    src+c0+ 8, src+c0+16, src+c0+24,
                   src+c0+32, src+c0+40, src+c0+48, src+c0+56,
                   src+c0+64, src+c0+72, src+c0+80, src+c0+88);
          aput16(As,1536,m,c0,    d0);  aput16(As,1536,m,c0+ 8,d1);
          aput16(As,1536,m,c0+16, d2);  aput16(As,1536,m,c0+24,d3);
          aput16(As,1536,m,c0+32, d4);  aput16(As,1536,m,c0+40,d5);
          aput16(As,1536,m,c0+48, d6);  aput16(As,1536,m,c0+56,d7);
          aput16(As,1536,m,c0+64, d8);  aput16(As,1536,m,c0+72,d9);
          aput16(As,1536,m,c0+80, d10); aput16(As,1536,m,c0+88,d11);
        }
      }
      __syncthreads();
      const int jjt = jjg*2 + (wv & 1), mt = wv >> 1;
      const int jj = jjt*16 + c16;
      // hoisted coherent gather of gatesHX (single 16-dword batch)
      float gx[16];
      {
        const float* a[16];
        #pragma unroll
        for (int r = 0; r < 4; r++){
          int b = b0 + mt*16 + q4*4 + r;
          size_t g0 = (size_t)b*3072 + jj;
          a[r*4+0] = p.gatesHX + g0;        a[r*4+1] = p.gatesHX + g0 + 768;
          a[r*4+2] = p.gatesHX + g0 + 1536; a[r*4+3] = p.gatesHX + g0 + 2304;
        }
        cldd16(gx, a[0],a[1],a[2],a[3],a[4],a[5],a[6],a[7],
                   a[8],a[9],a[10],a[11],a[12],a[13],a[14],a[15]);
      }
      f4 acc[4];
      #pragma unroll
      for (int g = 0; g < 4; g++) acc[g] = f4{0.f,0.f,0.f,0.f};
      short8 bfc[4];
      #pragma unroll
      for (int g = 0; g < 4; g++)
        bfc[g] = *(const short8*)(p.Wcomb_s + ((size_t)(0*192 + g*48 + jjt))*512 + lane*8);
      for (int kb = 0; kb < 48; kb++){
        int kbn = (kb < 47) ? kb + 1 : kb;
        short8 bfn[4];
        #pragma unroll
        for (int g = 0; g < 4; g++)
          bfn[g] = *(const short8*)(p.Wcomb_s + ((size_t)(kbn*192 + g*48 + jjt))*512 + lane*8);
        short8 af = afrag(As, 1536, mt*16 + c16, kb, q4);
        #pragma unroll
        for (int g = 0; g < 4; g++) acc[g] = mfma16(af, bfc[g], acc[g]);
        #pragma unroll
        for (int g = 0; g < 4; g++) bfc[g] = bfn[g];
      }
      float bfw[4];
      #pragma unroll
      for (int g = 0; g < 4; g++) bfw[g] = p.bfW[g*768 + jj];
      #pragma unroll
      for (int r = 0; r < 4; r++){
        int b = b0 + mt*16 + q4*4 + r;
        int pt = p.ping[b*T_ + t];
        bool cond = (pt > 0) && (t > 0);
        size_t g0 = (size_t)b*3072 + jj;
        float gi = p.base[g0]      + gx[r*4+0];
        float gf = p.base[g0+768]  + gx[r*4+1];
        float gg = p.base[g0+1536] + gx[r*4+2];
        float go = p.base[g0+2304] + gx[r*4+3];
        if (cond){
          gi += acc[0][r] + bfw[0]; gf += acc[1][r] + bfw[1];
          gg += acc[2][r] + bfw[2]; go += acc[3][r] + bfw[3];
        }
        float co = p.cbuf[b*768 + jj];
        float cn = sigm(gf)*co + sigm(gi)*tanh_(gg);
        float hh = sigm(go)*tanh_(cn);
        p.out[((size_t)(t*64 + b))*768 + jj] = hh;
        p.cbuf[b*768 + jj] = cn;
        float hp = __shfl_xor(hh, 1);
        if (!(c16 & 1))
          cst32((u32t*)(p.hB + (size_t)b*768 + jj), (u32t)f2b(hh) | ((u32t)f2b(hp) << 16));
        if (t == T_-1){
          p.out[HALL + b*768 + jj] = hh;
          p.out[HALL + 49152 + b*768 + jj] = cn;
        }
      }
    } else {
      // fuse: pairing (48+k, 56+k) for ng<8 (partial)
      const int local = blk - 48;
      int ng, mh;
      if (local < 16){ ng = local & 7; mh = local >> 3; }
      else { int l2 = local - 16; ng = 8 + (l2 & 3); mh = l2 >> 2; }
      const int b0 = mh*32;
      {
        int m = tid0 >> 3, j = tid0 & 7;
        const f4* src = (const f4*)(p.ctxb + (size_t)(b0+m)*1536);
        #pragma unroll
        for (int g = 0; g < 2; g++){
          f4 d0,d1,d2,d3,d4,d5,d6,d7,d8,d9,d10,d11;
          int c0 = j + 96*g;
          cldx4_12(d0,d1,d2,d3,d4,d5,d6,d7,d8,d9,d10,d11,
                   src+c0,    src+c0+ 8, src+c0+16, src+c0+24,
                   src+c0+32, src+c0+40, src+c0+48, src+c0+56,
                   src+c0+64, src+c0+72, src+c0+80, src+c0+88);
          aput16(As,1536,m,c0,    d0);  aput16(As,1536,m,c0+ 8,d1);
          aput16(As,1536,m,c0+16, d2);  aput16(As,1536,m,c0+24,d3);
          aput16(As,1536,m,c0+32, d4);  aput16(As,1536,m,c0+40,d5);
          aput16(As,1536,m,c0+48, d6);  aput16(As,1536,m,c0+56,d7);
          aput16(As,1536,m,c0+64, d8);  aput16(As,1536,m,c0+72,d9);
          aput16(As,1536,m,c0+80, d10); aput16(As,1536,m,c0+88,d11);
        }
      }
      __syncthreads();
      const int nt = ng*4 + wv;
      f4 acc[2];
      #pragma unroll
      for (int mt = 0; mt < 2; mt++) acc[mt] = f4{0.f,0.f,0.f,0.f};
      short8 bfc = *(const short8*)(p.Wfuse_s + ((size_t)(0*48 + nt))*512 + lane*8);
      for (int kb = 0; kb < 48; kb++){
        int kbn = (kb < 47) ? kb + 1 : kb;
        short8 bfn = *(const short8*)(p.Wfuse_s + ((size_t)(kbn*48 + nt))*512 + lane*8);
        #pragma unroll
        for (int mt = 0; mt < 2; mt++){
          short8 af = afrag(As, 1536, mt*16 + c16, kb, q4);
          acc[mt] = mfma16(af, bfc, acc[mt]);
        }
        bfc = bfn;
      }
      const int n = nt*16 + c16;
      const float bias = p.bfuse[n];
      #pragma unroll
      for (int mt = 0; mt < 2; mt++)
        #pragma unroll
        for (int r = 0; r < 4; r++){
          int b = b0 + mt*16 + q4*4 + r;
          int pt = p.ping[b*T_ + t];
          float v = acc[mt][r] + bias;
          float v2 = __shfl_xor(v, 1);
          if ((pt > 0) && (t > 0) && !(c16 & 1))
            cst32((u32t*)(p.xB + ((size_t)(t*64 + b))*768 + n),
                  (u32t)f2b(v) | ((u32t)f2b(v2) << 16));
        }
    }
    e++; gsync(p.flags, p.gen, e);
  }
}

extern "C" void kernel_launch(void* const* d_in, const int* in_sizes, int n_in,
                              void* d_out, int out_size, void* d_ws, size_t ws_size,
                              hipStream_t stream)
{
  (void)in_sizes; (void)n_in; (void)out_size; (void)ws_size;
  char* ws = (char*)d_ws;
  size_t off = 0;
  auto take = [&](size_t bytes)->void*{
    void* ptr = ws + off;
    off += (bytes + 255) & ~(size_t)255;
    return ptr;
  };

  Params p;
  p.question = (const float*)d_in[0];
  p.answer   = (const float*)d_in[1];
  p.x        = (const float*)d_in[2];
  p.ping     = (const int*)d_in[3];
  p.h0  = (const float*)d_in[4];  p.c0  = (const float*)d_in[5];
  p.Wqh = (const float*)d_in[6];  p.bqh = (const float*)d_in[7];
  p.Wah = (const float*)d_in[8];  p.bah = (const float*)d_in[9];
  p.Wih = (const float*)d_in[10]; p.bih = (const float*)d_in[11];
  p.Whh = (const float*)d_in[12]; p.bhh = (const float*)d_in[13];
  p.Wq  = (const float*)d_in[14]; p.bq  = (const float*)d_in[15];
  p.Wk  = (const float*)d_in[16]; p.bk  = (const float*)d_in[17];
  p.Wv  = (const float*)d_in[18]; p.bv  = (const float*)d_in[19];
  p.Wfuse = (const float*)d_in[20]; p.bfuse = (const float*)d_in[21];
  p.out = (float*)d_out;

  u32t* sync = (u32t*)take(16384);
  p.flags = sync;
  p.gen   = sync + 3072;

  p.Wqkv_s   = (u16t*)take((size_t)221184*16);
  p.Whhih_s  = (u16t*)take((size_t)589824*16);
  p.Wfuse_s  = (u16t*)take((size_t)147456*16);
  p.Wcomb_s  = (u16t*)take((size_t)589824*16);
  p.Wfuse_bf = (u16t*)take((size_t)1536*768*2);
  p.base     = (float*)take((size_t)64*3072*4);
  p.gatesHX  = (float*)take((size_t)64*3072*4);
  p.ctxb     = (u16t*)take((size_t)64*1536*2);
  p.hB       = (u16t*)take((size_t)64*768*2);
  p.cbuf     = (float*)take((size_t)64*768*4);
  p.bfW      = (float*)take((size_t)3072*4);
  p.xB       = (u16t*)take((size_t)12582912*2);

  hipFuncSetAttribute(reinterpret_cast<const void*>(sqac_kernel),
                      hipFuncAttributeMaxDynamicSharedMemorySize, 98304);
  hipMemsetAsync(sync, 0, 16384, stream);
  hipLaunchKernelGGL(sqac_kernel, dim3(NBLK), dim3(NTHR), 98304, stream, p);
}

// Round 11
// 17094.818 us; speedup vs baseline: 1.4284x; 1.0373x over previous
//
#include <hip/hip_runtime.h>
#include <cstdint>
#include <cstddef>

// SQACILSTM round 15 = exact restore of round 11 (best verified: 17.13ms,
// FETCH 1.25e6 KB). r14's bundle (wider batches + B-prefetch) REGRESSED:
// FETCH 1.25->3.10e6 KB (Wcomb L2 residency partially broken, likely by the
// prefetch's deeper in-flight window), dur +0.6ms. Session model, verified:
// dur = ~0.26us/MB * FETCH + ~60us/step serial base; the 72x256 shape is
// load-bearing (blk%8->XCD pairing breaks at other shapes, r13); 2 grid
// barriers/step are structural (attn->cell crosses block partition, h
// recurrence crosses steps); all TLP routes require shape changes that
// destroy L2 residency (r6-9, r12-13). This artifact: x->bf16 mirror +
// anyX gate-skip (r10) + XCD-aware role pairing + 16B staging (r11).

#define T_   256
#define B_   64
#define NBLK 72
#define NTHR 256
#define GRIDTH (NBLK*NTHR)
#define HALL 12582912   // 256*64*768

typedef __attribute__((ext_vector_type(8))) short short8;
typedef __attribute__((ext_vector_type(4))) float f4;
typedef unsigned long long u64t;
typedef unsigned short u16t;
typedef unsigned int u32t;

struct Params {
  const float* question; const float* answer; const float* x; const int* ping;
  const float* h0; const float* c0;
  const float* Wqh; const float* bqh; const float* Wah; const float* bah;
  const float* Wih; const float* bih; const float* Whh; const float* bhh;
  const float* Wq;  const float* bq;  const float* Wk;  const float* bk;
  const float* Wv;  const float* bv;  const float* Wfuse; const float* bfuse;
  float* out;
  u32t* flags; u32t* gen;
  u16t* Wqkv_s; u16t* Whhih_s; u16t* Wfuse_s; u16t* Wcomb_s; u16t* Wfuse_bf;
  float* base; float* gatesHX; u16t* ctxb; u16t* hB; float* cbuf; float* bfW;
  u16t* xB;
};

__device__ __forceinline__ u16t f2b(float f){
  union { float f; u32t u; } a; a.f = f;
  u32t u = a.u;
  u32t r = u + 0x7FFFu + ((u >> 16) & 1u);
  return (u16t)(r >> 16);
}
__device__ __forceinline__ float b2f(u16t u){
  union { u32t u; float f; } a; a.u = ((u32t)u) << 16; return a.f;
}
__device__ __forceinline__ u64t pack4f(float a, float b, float c, float d){
  return (u64t)f2b(a) | ((u64t)f2b(b)<<16) | ((u64t)f2b(c)<<32) | ((u64t)f2b(d)<<48);
}
__device__ __forceinline__ float sigm(float x){ return 1.0f/(1.0f+__expf(-x)); }
__device__ __forceinline__ float tanh_(float x){ return 2.0f/(1.0f+__expf(-2.0f*x)) - 1.0f; }
__device__ __forceinline__ f4 mfma16(short8 a, short8 b, f4 c){
  return __builtin_amdgcn_mfma_f32_16x16x32_bf16(a, b, c, 0, 0, 0);
}
__device__ __forceinline__ float wsum(float x){
  #pragma unroll
  for (int off = 32; off > 0; off >>= 1) x += __shfl_xor(x, off, 64);
  return x;
}

// ---- batched coherent loads (LLC / sc0 sc1), one waitcnt per batch ----
__device__ __forceinline__ void cldx4_8(f4&d0,f4&d1,f4&d2,f4&d3,f4&d4,f4&d5,f4&d6,f4&d7,
  const void*a0,const void*a1,const void*a2,const void*a3,
  const void*a4,const void*a5,const void*a6,const void*a7){
  asm volatile(
    "global_load_dwordx4 %0, %8, off sc0 sc1\n\t"
    "global_load_dwordx4 %1, %9, off sc0 sc1\n\t"
    "global_load_dwordx4 %2, %10, off sc0 sc1\n\t"
    "global_load_dwordx4 %3, %11, off sc0 sc1\n\t"
    "global_load_dwordx4 %4, %12, off sc0 sc1\n\t"
    "global_load_dwordx4 %5, %13, off sc0 sc1\n\t"
    "global_load_dwordx4 %6, %14, off sc0 sc1\n\t"
    "global_load_dwordx4 %7, %15, off sc0 sc1\n\t"
    "s_waitcnt vmcnt(0)"
    : "=&v"(d0),"=&v"(d1),"=&v"(d2),"=&v"(d3),"=&v"(d4),"=&v"(d5),"=&v"(d6),"=&v"(d7)
    : "v"(a0),"v"(a1),"v"(a2),"v"(a3),"v"(a4),"v"(a5),"v"(a6),"v"(a7));
}
__device__ __forceinline__ void cldx4_4(f4&d0,f4&d1,f4&d2,f4&d3,
  const void*a0,const void*a1,const void*a2,const void*a3){
  asm volatile(
    "global_load_dwordx4 %0, %4, off sc0 sc1\n\t"
    "global_load_dwordx4 %1, %5, off sc0 sc1\n\t"
    "global_load_dwordx4 %2, %6, off sc0 sc1\n\t"
    "global_load_dwordx4 %3, %7, off sc0 sc1\n\t"
    "s_waitcnt vmcnt(0)"
    : "=&v"(d0),"=&v"(d1),"=&v"(d2),"=&v"(d3)
    : "v"(a0),"v"(a1),"v"(a2),"v"(a3));
}
__device__ __forceinline__ void cldd8(float&d0,float&d1,float&d2,float&d3,float&d4,float&d5,float&d6,float&d7,
  const float*a0,const float*a1,const float*a2,const float*a3,
  const float*a4,const float*a5,const float*a6,const float*a7){
  asm volatile(
    "global_load_dword %0, %8, off sc0 sc1\n\t"
    "global_load_dword %1, %9, off sc0 sc1\n\t"
    "global_load_dword %2, %10, off sc0 sc1\n\t"
    "global_load_dword %3, %11, off sc0 sc1\n\t"
    "global_load_dword %4, %12, off sc0 sc1\n\t"
    "global_load_dword %5, %13, off sc0 sc1\n\t"
    "global_load_dword %6, %14, off sc0 sc1\n\t"
    "global_load_dword %7, %15, off sc0 sc1\n\t"
    "s_waitcnt vmcnt(0)"
    : "=&v"(d0),"=&v"(d1),"=&v"(d2),"=&v"(d3),"=&v"(d4),"=&v"(d5),"=&v"(d6),"=&v"(d7)
    : "v"(a0),"v"(a1),"v"(a2),"v"(a3),"v"(a4),"v"(a5),"v"(a6),"v"(a7));
}

// ---- coherent stores (fire-and-forget; drained by barrier's vmcnt wait) ----
__device__ __forceinline__ void cstf(float* p, float v){
  __hip_atomic_store(p, v, __ATOMIC_RELAXED, __HIP_MEMORY_SCOPE_AGENT);
}
__device__ __forceinline__ void cst32(u32t* p, u32t v){
  __hip_atomic_store(p, v, __ATOMIC_RELAXED, __HIP_MEMORY_SCOPE_AGENT);
}

// ---- LDS A-tile, XOR-swizzled 16B chunks ----
// chunk index cc (16B units within a row); slot = (cc&~7)|((cc^m)&7)
__device__ __forceinline__ void aput16(u16t* As, int rowu16, int m, int cc, f4 v){
  int slot = (cc & ~7) | ((cc ^ m) & 7);
  *(f4*)(As + m*rowu16 + slot*8) = v;
}
__device__ __forceinline__ short8 afrag(const u16t* As, int rowu16, int m, int kb, int q4){
  int c = kb*4 + q4;
  int phys = (c & ~7) | ((c ^ m) & 7);
  return *(const short8*)(As + m*rowu16 + phys*8);
}

// ---- grid barrier: relaxed agent atomics only, no cache invalidation ----
__device__ __forceinline__ void gsync(u32t* flags, u32t* gen, u32t e){
  asm volatile("s_waitcnt vmcnt(0) lgkmcnt(0)" ::: "memory");
  __syncthreads();
  if (blockIdx.x == 0){
    if (threadIdx.x > 0 && threadIdx.x < NBLK){
      while (__hip_atomic_load(flags + threadIdx.x*32, __ATOMIC_RELAXED, __HIP_MEMORY_SCOPE_AGENT) < e) ;
    }
    __syncthreads();
    if (threadIdx.x == 0)
      __hip_atomic_store(gen, e, __ATOMIC_RELAXED, __HIP_MEMORY_SCOPE_AGENT);
  } else {
    if (threadIdx.x == 0){
      __hip_atomic_store(flags + blockIdx.x*32, e, __ATOMIC_RELAXED, __HIP_MEMORY_SCOPE_AGENT);
      while (__hip_atomic_load(gen, __ATOMIC_RELAXED, __HIP_MEMORY_SCOPE_AGENT) < e) ;
    }
  }
  __builtin_amdgcn_fence(__ATOMIC_ACQUIRE, "workgroup");
  __syncthreads();
}

__launch_bounds__(NTHR, 1)
__global__ void sqac_kernel(Params p){
  extern __shared__ u16t As[];           // 96KB dynamic A-tile
  __shared__ u16t qkvs[64*192];          // 24KB qkv exchange
  __shared__ int anyX;                   // gates: any !cond row in this block?
  const int tid0 = threadIdx.x;
  const int blk  = blockIdx.x;
  const int tid  = blk*NTHR + tid0;
  const int lane = tid0 & 63;
  const int wv   = tid0 >> 6;
  const int c16  = lane & 15, q4 = lane >> 4;
  u32t e = 0;

  // ================= P0 stage 1: conversions / swizzles / base =================
  {
    for (int idx = tid; idx < 12288; idx += GRIDTH){
      f4 h = *(const f4*)(p.h0 + idx*4);
      *(u64t*)(p.hB + idx*4) = pack4f(h.x, h.y, h.z, h.w);
      *(f4*)(p.cbuf + idx*4) = *(const f4*)(p.c0 + idx*4);
    }
    // x -> bf16 mirror (all consumers convert to bf16 anyway; bit-identical)
    for (int idx = tid; idx < 3145728; idx += GRIDTH){
      f4 v = *(const f4*)(p.x + (size_t)idx*4);
      *(u64t*)(p.xB + (size_t)idx*4) = pack4f(v.x, v.y, v.z, v.w);
    }
    for (int idx = tid; idx < 221184; idx += GRIDTH){
      int l = idx & 63, g2 = idx >> 6;
      int ntl = g2 % 12, kb = (g2/12) % 24, h = g2/288;
      int k0 = kb*32 + ((l>>4)<<3);
      int nl = ntl*16 + (l&15);
      const float* s; int col;
      if (nl < 64){ s = p.Wq; col = h*64 + nl; }
      else if (nl < 128){ s = p.Wk; col = h*64 + nl - 64; }
      else { s = p.Wv; col = h*64 + nl - 128; }
      union { u16t a[8]; short8 v; } t8;
      #pragma unroll
      for (int j = 0; j < 8; j++) t8.a[j] = f2b(s[(size_t)(k0+j)*768 + col]);
      *(short8*)(p.Wqkv_s + (size_t)idx*8) = t8.v;
    }
    for (int idx = tid; idx < 589824; idx += GRIDTH){
      int l = idx & 63, g2 = idx >> 6;
      int nb = g2 % 192, kb2 = g2 / 192;
      int n  = nb*16 + (l&15);
      int kl = (kb2 % 24)*32 + ((l>>4)<<3);
      const float* s = (kb2 < 24) ? p.Whh : p.Wih;
      union { u16t a[8]; short8 v; } t8;
      #pragma unroll
      for (int j = 0; j < 8; j++) t8.a[j] = f2b(s[(size_t)(kl+j)*3072 + n]);
      *(short8*)(p.Whhih_s + (size_t)idx*8) = t8.v;
    }
    for (int idx = tid; idx < 147456; idx += GRIDTH){
      int l = idx & 63, g2 = idx >> 6;
      int nb = g2 % 48, kb = g2 / 48;
      int n  = nb*16 + (l&15);
      int k0 = kb*32 + ((l>>4)<<3);
      union { u16t a[8]; short8 v; } t8;
      #pragma unroll
      for (int j = 0; j < 8; j++) t8.a[j] = f2b(p.Wfuse[(size_t)(k0+j)*768 + n]);
      *(short8*)(p.Wfuse_s + (size_t)idx*8) = t8.v;
    }
    for (int idx = tid; idx < 294912; idx += GRIDTH){
      f4 v = *(const f4*)(p.Wfuse + idx*4);
      *(u64t*)(p.Wfuse_bf + idx*4) = pack4f(v.x, v.y, v.z, v.w);
    }
    for (int w = tid; w < 24576; w += GRIDTH){
      int bg = w / 3072, n = w - bg*3072;
      float acc[8];
      #pragma unroll
      for (int bi = 0; bi < 8; bi++) acc[bi] = 0.f;
      for (int k = 0; k < 768; k++){
        float wq = p.Wqh[(size_t)k*3072 + n];
        float wa = p.Wah[(size_t)k*3072 + n];
        #pragma unroll
        for (int bi = 0; bi < 8; bi++){
          int b = bg*8 + bi;
          acc[bi] += p.question[b*768 + k]*wq + p.answer[b*768 + k]*wa;
        }
      }
      float bias = p.bqh[n] + p.bah[n] + p.bih[n] + p.bhh[n];
      #pragma unroll
      for (int bi = 0; bi < 8; bi++)
        p.base[(size_t)(bg*8+bi)*3072 + n] = acc[bi] + bias;
    }
    for (int n = tid; n < 3072; n += GRIDTH){
      float a = 0.f;
      for (int k = 0; k < 768; k++) a += p.bfuse[k]*p.Wih[(size_t)k*3072 + n];
      p.bfW[n] = a;
    }
  }
  __threadfence();
  e++; gsync(p.flags, p.gen, e);

  // ================= P0 stage 2: Wcomb = Wfuse @ Wih (MFMA) =================
  {
    int w = tid >> 6;
    int mt = w % 96, ntg = w / 96;
    for (int nt = ntg*64; nt < ntg*64 + 64; nt++){
      f4 acc = {0.f,0.f,0.f,0.f};
      for (int kb = 0; kb < 24; kb++){
        short8 af = *(const short8*)(p.Wfuse_bf + (size_t)(mt*16 + c16)*768 + kb*32 + q4*8);
        short8 bf = *(const short8*)(p.Whhih_s + ((size_t)((24+kb)*192 + nt))*512 + lane*8);
        acc = mfma16(af, bf, acc);
      }
      #pragma unroll
      for (int r = 0; r < 4; r++){
        int k1 = mt*16 + q4*4 + r;
        p.Wcomb_s[((size_t)((k1>>5)*192 + nt))*512 + (size_t)((((k1>>3)&3)*16 + c16)*8 + (k1&7))] = f2b(acc[r]);
      }
    }
  }
  __threadfence();
  e++; gsync(p.flags, p.gen, e);

  // ================= main scan: 2 barriers per step =================
  for (int t = 0; t < T_; t++){

    // ---------- PA ----------
    if (blk < 24){
      // XCD-aware pairing: (k, k+8) share h for h<8 (same XCD since blk%8
      // dispatch); heads 8..11 on blocks 16..23 (unpaired residual).
      int h, bh;
      if (blk < 16){ h = blk & 7; bh = blk >> 3; }
      else { int l2 = blk - 16; h = 8 + (l2 & 3); bh = l2 >> 2; }
      {
        int m = tid0 >> 2, j = tid0 & 3;      // 64 rows, 4 thr/row, 96 chunks/row
        int b = bh*32 + (m & 31);
        int st;
        if (m < 32){ int pt = p.ping[b*T_ + t]; st = pt - 1; if (st < 0) st = 0; if (st > T_-1) st = T_-1; }
        else st = t;
        const f4* src = (const f4*)(p.xB + ((size_t)(st*64 + b))*768);
        #pragma unroll
        for (int g = 0; g < 3; g++){
          f4 d0,d1,d2,d3,d4,d5,d6,d7;
          int c0 = j + 32*g;                  // cc = c0 + 4i, i=0..7
          cldx4_8(d0,d1,d2,d3,d4,d5,d6,d7,
                  src+c0,    src+c0+ 4, src+c0+ 8, src+c0+12,
                  src+c0+16, src+c0+20, src+c0+24, src+c0+28);
          aput16(As,768,m,c0,    d0); aput16(As,768,m,c0+ 4,d1);
          aput16(As,768,m,c0+ 8, d2); aput16(As,768,m,c0+12,d3);
          aput16(As,768,m,c0+16, d4); aput16(As,768,m,c0+20,d5);
          aput16(As,768,m,c0+24, d6); aput16(As,768,m,c0+28,d7);
        }
      }
      __syncthreads();
      f4 acc[3][4];
      #pragma unroll
      for (int i = 0; i < 3; i++)
        #pragma unroll
        for (int mt = 0; mt < 4; mt++) acc[i][mt] = f4{0.f,0.f,0.f,0.f};
      for (int kb = 0; kb < 24; kb++){
        short8 af[4];
        #pragma unroll
        for (int mt = 0; mt < 4; mt++) af[mt] = afrag(As, 768, mt*16 + c16, kb, q4);
        #pragma unroll
        for (int i = 0; i < 3; i++){
          short8 bf = *(const short8*)(p.Wqkv_s + ((size_t)((h*24 + kb)*12 + wv*3 + i))*512 + lane*8);
          #pragma unroll
          for (int mt = 0; mt < 4; mt++) acc[i][mt] = mfma16(af[mt], bf, acc[i][mt]);
        }
      }
      #pragma unroll
      for (int i = 0; i < 3; i++){
        int nl = (wv*3 + i)*16 + c16;
        float bias = (nl < 64) ? p.bq[h*64+nl] : (nl < 128 ? p.bk[h*64+nl-64] : p.bv[h*64+nl-128]);
        #pragma unroll
        for (int mt = 0; mt < 4; mt++)
          #pragma unroll
          for (int r = 0; r < 4; r++)
            qkvs[(mt*16 + q4*4 + r)*192 + nl] = f2b(acc[i][mt][r] + bias);
      }
      __syncthreads();
      for (int pi = 0; pi < 8; pi++){
        int bi = wv*8 + pi;
        const u16t* L = qkvs + bi*192;
        const u16t* R = qkvs + (32+bi)*192;
        float ql = b2f(L[lane]), kl = b2f(L[64+lane]), vl = b2f(L[128+lane]);
        float qr = b2f(R[lane]), kr = b2f(R[64+lane]), vr = b2f(R[128+lane]);
        float sll = wsum(ql*kl)*0.125f, slr = wsum(ql*kr)*0.125f;
        float srl = wsum(qr*kl)*0.125f, srr = wsum(qr*kr)*0.125f;
        float ml = fmaxf(sll, slr), mr = fmaxf(srl, srr);
        float ell = __expf(sll-ml), elr = __expf(slr-ml);
        float erl = __expf(srl-mr), err = __expf(srr-mr);
        float il = 1.0f/(ell+elr), ir = 1.0f/(erl+err);
        float cl = (ell*il)*vl + (elr*il)*vr;
        float cr = (erl*ir)*vl + (err*ir)*vr;
        float cl2 = __shfl_xor(cl, 1), cr2 = __shfl_xor(cr, 1);
        if (!(lane & 1)){
          int b = bh*32 + bi;
          cst32((u32t*)(p.ctxb + (size_t)b*1536 + h*64 + lane),
                (u32t)f2b(cl) | ((u32t)f2b(cl2) << 16));
          cst32((u32t*)(p.ctxb + (size_t)b*1536 + 768 + h*64 + lane),
                (u32t)f2b(cr) | ((u32t)f2b(cr2) << 16));
        }
      }
    } else {
      // gatesHX = [h | masked_x] @ vstack(Whh, Wih)
      // XCD pairing: (24+n, 48+n) share ng=n (48-24 = 24 ≡ 0 mod 8).
      const int local = blk - 24, mh = local / 24, ng = local % 24;
      const int b0 = mh*32;
      if (tid0 == 0) anyX = 0;
      __syncthreads();
      {
        int m = tid0 >> 3, j = tid0 & 7;     // 32 rows, 8 thr/row, 96 chunks/row
        int b = b0 + m;
        int pt = p.ping[b*T_ + t];
        bool cond = (pt > 0) && (t > 0);
        const f4* hsrc = (const f4*)(p.hB + (size_t)b*768);
        {
          f4 d0,d1,d2,d3,d4,d5,d6,d7;
          cldx4_8(d0,d1,d2,d3,d4,d5,d6,d7,
                  hsrc+j,    hsrc+j+ 8, hsrc+j+16, hsrc+j+24,
                  hsrc+j+32, hsrc+j+40, hsrc+j+48, hsrc+j+56);
          aput16(As,1536,m,j,    d0); aput16(As,1536,m,j+ 8,d1);
          aput16(As,1536,m,j+16, d2); aput16(As,1536,m,j+24,d3);
          aput16(As,1536,m,j+32, d4); aput16(As,1536,m,j+40,d5);
          aput16(As,1536,m,j+48, d6); aput16(As,1536,m,j+56,d7);
          f4 e0,e1,e2,e3;
          cldx4_4(e0,e1,e2,e3, hsrc+j+64, hsrc+j+72, hsrc+j+80, hsrc+j+88);
          aput16(As,1536,m,j+64, e0); aput16(As,1536,m,j+72,e1);
          aput16(As,1536,m,j+80, e2); aput16(As,1536,m,j+88,e3);
        }
        if (cond){
          #pragma unroll
          for (int i = 0; i < 12; i++) aput16(As,1536,m,96 + j + 8*i, f4{0.f,0.f,0.f,0.f});
        } else {
          if (j == 0) anyX = 1;
          const f4* xsrc = (const f4*)(p.xB + ((size_t)(t*64 + b))*768);
          f4 d0,d1,d2,d3,d4,d5,d6,d7;
          cldx4_8(d0,d1,d2,d3,d4,d5,d6,d7,
                  xsrc+j,    xsrc+j+ 8, xsrc+j+16, xsrc+j+24,
                  xsrc+j+32, xsrc+j+40, xsrc+j+48, xsrc+j+56);
          aput16(As,1536,m,96+j,    d0); aput16(As,1536,m,96+j+ 8,d1);
          aput16(As,1536,m,96+j+16, d2); aput16(As,1536,m,96+j+24,d3);
          aput16(As,1536,m,96+j+32, d4); aput16(As,1536,m,96+j+40,d5);
          aput16(As,1536,m,96+j+48, d6); aput16(As,1536,m,96+j+56,d7);
          f4 e0,e1,e2,e3;
          cldx4_4(e0,e1,e2,e3, xsrc+j+64, xsrc+j+72, xsrc+j+80, xsrc+j+88);
          aput16(As,1536,m,96+j+64, e0); aput16(As,1536,m,96+j+72,e1);
          aput16(As,1536,m,96+j+80, e2); aput16(As,1536,m,96+j+88,e3);
        }
      }
      __syncthreads();
      const int kbmax = anyX ? 48 : 24;     // x-half is all zeros when !anyX
      f4 acc[2][2];
      #pragma unroll
      for (int i = 0; i < 2; i++)
        #pragma unroll
        for (int mt = 0; mt < 2; mt++) acc[i][mt] = f4{0.f,0.f,0.f,0.f};
      for (int kb = 0; kb < kbmax; kb++){
        short8 af[2];
        #pragma unroll
        for (int mt = 0; mt < 2; mt++) af[mt] = afrag(As, 1536, mt*16 + c16, kb, q4);
        #pragma unroll
        for (int i = 0; i < 2; i++){
          int nt = ng*8 + wv*2 + i;
          short8 bf = *(const short8*)(p.Whhih_s + ((size_t)(kb*192 + nt))*512 + lane*8);
          #pragma unroll
          for (int mt = 0; mt < 2; mt++) acc[i][mt] = mfma16(af[mt], bf, acc[i][mt]);
        }
      }
      #pragma unroll
      for (int i = 0; i < 2; i++){
        int n = (ng*8 + wv*2 + i)*16 + c16;
        #pragma unroll
        for (int mt = 0; mt < 2; mt++)
          #pragma unroll
          for (int r = 0; r < 4; r++){
            int b = b0 + mt*16 + q4*4 + r;
            cstf(p.gatesHX + (size_t)b*3072 + n, acc[i][mt][r]);
          }
      }
    }
    e++; gsync(p.flags, p.gen, e);

    // ---------- PB ----------
    if (blk < 48){
      // XCD pairing: (k, k+24) share jjg=k (24 ≡ 0 mod 8).
      const int mh = blk / 24, jjg = blk % 24;
      const int b0 = mh*32;
      {
        int m = tid0 >> 3, j = tid0 & 7;     // 32 rows, 8 thr/row, 192 chunks/row
        const f4* src = (const f4*)(p.ctxb + (size_t)(b0+m)*1536);
        #pragma unroll
        for (int g = 0; g < 3; g++){
          f4 d0,d1,d2,d3,d4,d5,d6,d7;
          int c0 = j + 64*g;                  // cc = c0 + 8i, i=0..7
          cldx4_8(d0,d1,d2,d3,d4,d5,d6,d7,
                  src+c0,    src+c0+ 8, src+c0+16, src+c0+24,
                  src+c0+32, src+c0+40, src+c0+48, src+c0+56);
          aput16(As,1536,m,c0,    d0); aput16(As,1536,m,c0+ 8,d1);
          aput16(As,1536,m,c0+16, d2); aput16(As,1536,m,c0+24,d3);
          aput16(As,1536,m,c0+32, d4); aput16(As,1536,m,c0+40,d5);
          aput16(As,1536,m,c0+48, d6); aput16(As,1536,m,c0+56,d7);
        }
      }
      __syncthreads();
      const int jjt = jjg*2 + (wv & 1), mt = wv >> 1;
      const int jj = jjt*16 + c16;
      // hoisted coherent gather of gatesHX
      float gx[16];
      {
        const float* a[16];
        #pragma unroll
        for (int r = 0; r < 4; r++){
          int b = b0 + mt*16 + q4*4 + r;
          size_t g0 = (size_t)b*3072 + jj;
          a[r*4+0] = p.gatesHX + g0;        a[r*4+1] = p.gatesHX + g0 + 768;
          a[r*4+2] = p.gatesHX + g0 + 1536; a[r*4+3] = p.gatesHX + g0 + 2304;
        }
        cldd8(gx[0],gx[1],gx[2],gx[3],gx[4],gx[5],gx[6],gx[7],
              a[0],a[1],a[2],a[3],a[4],a[5],a[6],a[7]);
        cldd8(gx[8],gx[9],gx[10],gx[11],gx[12],gx[13],gx[14],gx[15],
              a[8],a[9],a[10],a[11],a[12],a[13],a[14],a[15]);
      }
      f4 acc[4];
      #pragma unroll
      for (int g = 0; g < 4; g++) acc[g] = f4{0.f,0.f,0.f,0.f};
      for (int kb = 0; kb < 48; kb++){
        short8 af = afrag(As, 1536, mt*16 + c16, kb, q4);
        #pragma unroll
        for (int g = 0; g < 4; g++){
          short8 bf = *(const short8*)(p.Wcomb_s + ((size_t)(kb*192 + g*48 + jjt))*512 + lane*8);
          acc[g] = mfma16(af, bf, acc[g]);
        }
      }
      float bfw[4];
      #pragma unroll
      for (int g = 0; g < 4; g++) bfw[g] = p.bfW[g*768 + jj];
      #pragma unroll
      for (int r = 0; r < 4; r++){
        int b = b0 + mt*16 + q4*4 + r;
        int pt = p.ping[b*T_ + t];
        bool cond = (pt > 0) && (t > 0);
        size_t g0 = (size_t)b*3072 + jj;
        float gi = p.base[g0]      + gx[r*4+0];
        float gf = p.base[g0+768]  + gx[r*4+1];
        float gg = p.base[g0+1536] + gx[r*4+2];
        float go = p.base[g0+2304] + gx[r*4+3];
        if (cond){
          gi += acc[0][r] + bfw[0]; gf += acc[1][r] + bfw[1];
          gg += acc[2][r] + bfw[2]; go += acc[3][r] + bfw[3];
        }
        float co = p.cbuf[b*768 + jj];
        float cn = sigm(gf)*co + sigm(gi)*tanh_(gg);
        float hh = sigm(go)*tanh_(cn);
        p.out[((size_t)(t*64 + b))*768 + jj] = hh;
        p.cbuf[b*768 + jj] = cn;
        float hp = __shfl_xor(hh, 1);
        if (!(c16 & 1))
          cst32((u32t*)(p.hB + (size_t)b*768 + jj), (u32t)f2b(hh) | ((u32t)f2b(hp) << 16));
        if (t == T_-1){
          p.out[HALL + b*768 + jj] = hh;
          p.out[HALL + 49152 + b*768 + jj] = cn;
        }
      }
    } else {
      // ctx @ Wfuse -> x update; pairing (48+k, 56+k) for ng<8 (partial)
      const int local = blk - 48;
      int ng, mh;
      if (local < 16){ ng = local & 7; mh = local >> 3; }
      else { int l2 = local - 16; ng = 8 + (l2 & 3); mh = l2 >> 2; }
      const int b0 = mh*32;
      {
        int m = tid0 >> 3, j = tid0 & 7;
        const f4* src = (const f4*)(p.ctxb + (size_t)(b0+m)*1536);
        #pragma unroll
        for (int g = 0; g < 3; g++){
          f4 d0,d1,d2,d3,d4,d5,d6,d7;
          int c0 = j + 64*g;
          cldx4_8(d0,d1,d2,d3,d4,d5,d6,d7,
                  src+c0,    src+c0+ 8, src+c0+16, src+c0+24,
                  src+c0+32, src+c0+40, src+c0+48, src+c0+56);
          aput16(As,1536,m,c0,    d0); aput16(As,1536,m,c0+ 8,d1);
          aput16(As,1536,m,c0+16, d2); aput16(As,1536,m,c0+24,d3);
          aput16(As,1536,m,c0+32, d4); aput16(As,1536,m,c0+40,d5);
          aput16(As,1536,m,c0+48, d6); aput16(As,1536,m,c0+56,d7);
        }
      }
      __syncthreads();
      const int nt = ng*4 + wv;
      f4 acc[2];
      #pragma unroll
      for (int mt = 0; mt < 2; mt++) acc[mt] = f4{0.f,0.f,0.f,0.f};
      for (int kb = 0; kb < 48; kb++){
        short8 bf = *(const short8*)(p.Wfuse_s + ((size_t)(kb*48 + nt))*512 + lane*8);
        #pragma unroll
        for (int mt = 0; mt < 2; mt++){
          short8 af = afrag(As, 1536, mt*16 + c16, kb, q4);
          acc[mt] = mfma16(af, bf, acc[mt]);
        }
      }
      const int n = nt*16 + c16;
      const float bias = p.bfuse[n];
      #pragma unroll
      for (int mt = 0; mt < 2; mt++)
        #pragma unroll
        for (int r = 0; r < 4; r++){
          int b = b0 + mt*16 + q4*4 + r;
          int pt = p.ping[b*T_ + t];
          float v = acc[mt][r] + bias;
          float v2 = __shfl_xor(v, 1);
          if ((pt > 0) && (t > 0) && !(c16 & 1))
            cst32((u32t*)(p.xB + ((size_t)(t*64 + b))*768 + n),
                  (u32t)f2b(v) | ((u32t)f2b(v2) << 16));
        }
    }
    e++; gsync(p.flags, p.gen, e);
  }
}

extern "C" void kernel_launch(void* const* d_in, const int* in_sizes, int n_in,
                              void* d_out, int out_size, void* d_ws, size_t ws_size,
                              hipStream_t stream)
{
  (void)in_sizes; (void)n_in; (void)out_size; (void)ws_size;
  char* ws = (char*)d_ws;
  size_t off = 0;
  auto take = [&](size_t bytes)->void*{
    void* ptr = ws + off;
    off += (bytes + 255) & ~(size_t)255;
    return ptr;
  };

  Params p;
  p.question = (const float*)d_in[0];
  p.answer   = (const float*)d_in[1];
  p.x        = (const float*)d_in[2];
  p.ping     = (const int*)d_in[3];
  p.h0  = (const float*)d_in[4];  p.c0  = (const float*)d_in[5];
  p.Wqh = (const float*)d_in[6];  p.bqh = (const float*)d_in[7];
  p.Wah = (const float*)d_in[8];  p.bah = (const float*)d_in[9];
  p.Wih = (const float*)d_in[10]; p.bih = (const float*)d_in[11];
  p.Whh = (const float*)d_in[12]; p.bhh = (const float*)d_in[13];
  p.Wq  = (const float*)d_in[14]; p.bq  = (const float*)d_in[15];
  p.Wk  = (const float*)d_in[16]; p.bk  = (const float*)d_in[17];
  p.Wv  = (const float*)d_in[18]; p.bv  = (const float*)d_in[19];
  p.Wfuse = (const float*)d_in[20]; p.bfuse = (const float*)d_in[21];
  p.out = (float*)d_out;

  u32t* sync = (u32t*)take(16384);
  p.flags = sync;
  p.gen   = sync + 3072;

  p.Wqkv_s   = (u16t*)take((size_t)221184*16);
  p.Whhih_s  = (u16t*)take((size_t)589824*16);
  p.Wfuse_s  = (u16t*)take((size_t)147456*16);
  p.Wcomb_s  = (u16t*)take((size_t)589824*16);
  p.Wfuse_bf = (u16t*)take((size_t)1536*768*2);
  p.base     = (float*)take((size_t)64*3072*4);
  p.gatesHX  = (float*)take((size_t)64*3072*4);
  p.ctxb     = (u16t*)take((size_t)64*1536*2);
  p.hB       = (u16t*)take((size_t)64*768*2);
  p.cbuf     = (float*)take((size_t)64*768*4);
  p.bfW      = (float*)take((size_t)3072*4);
  p.xB       = (u16t*)take((size_t)12582912*2);

  hipFuncSetAttribute(reinterpret_cast<const void*>(sqac_kernel),
                      hipFuncAttributeMaxDynamicSharedMemorySize, 98304);
  hipMemsetAsync(sync, 0, 16384, stream);
  hipLaunchKernelGGL(sqac_kernel, dim3(NBLK), dim3(NTHR), 98304, stream, p);
}